// Round 14
// baseline (14058.200 us; speedup 1.0000x reference)
//
#include <hip/hip_runtime.h>
#include <hip/hip_bf16.h>

// ---------------------------------------------------------------------------
// GRU, 2 layers, B=32, S=2048, D=H=512.
//   gemm:   ip0 = x @ Wi0^T + bi0   (bf16 MFMA)                [verified]
//   fused:  32 WGs. WG 0..15 = layer-0 rec, WG 16..31 = layer-1 rec.
//   r14 = r13 (passing, 13.61 ms) + flag ADDRESS-LAYOUT change only:
//     (a) one 64B line per (step, WG) flag  -> fl[(t*16+p)*16]   (was 16
//         flags packed in ONE line: 16 serialized writers + 2048 polling
//         lanes on a single hot LLC line per round);
//     (b) L1 polls a separate copy fl0b (written by L0 in the same drained
//         batch) so L0-peer and L1 polling don't share lines.
//   Protocol semantics (store/drain/barrier/poll order) byte-for-byte r13.
// ---------------------------------------------------------------------------

typedef __bf16    bf16x8 __attribute__((ext_vector_type(8)));
typedef __bf16    bf16x4 __attribute__((ext_vector_type(4)));
typedef float     f32x4  __attribute__((ext_vector_type(4)));
typedef _Float16  f16x2  __attribute__((ext_vector_type(2)));
typedef _Float16  f16x8  __attribute__((ext_vector_type(8)));

#define S_LEN 2048
#define BATCH 32
#define HID   512
#define G3    1536
#define MROWS (BATCH * S_LEN)
#define NWG   16
#define FPAD  16                  // dwords between flags: one 64B line each

__device__ inline float sigmoid_f(float x) { return 1.f / (1.f + __expf(-x)); }
__device__ inline float tanh_f(float x) {
  float e = __expf(2.f * x);
  return 1.f - 2.f / (e + 1.f);
}

template <typename IPT>
__device__ inline void store_ip(IPT* p, float v) {
  if constexpr (sizeof(IPT) == 4) *p = v;
  else *p = __builtin_bit_cast(unsigned short, (__bf16)v);
}
template <typename IPT>
__device__ inline float4 load_ip4(const IPT* p) {
  if constexpr (sizeof(IPT) == 4) {
    return *(const float4*)p;
  } else {
    ushort4 u = *(const ushort4*)p;
    float4 r;
    r.x = __uint_as_float((unsigned)u.x << 16);
    r.y = __uint_as_float((unsigned)u.y << 16);
    r.z = __uint_as_float((unsigned)u.z << 16);
    r.w = __uint_as_float((unsigned)u.w << 16);
    return r;
  }
}

// ---------------------------------------------------------------------------
// prep: Wi0 fp32 -> bf16 (for ip GEMM)
// ---------------------------------------------------------------------------
__global__ void prep_wib(const float* __restrict__ W, __bf16* __restrict__ o) {
  int i = blockIdx.x * 256 + threadIdx.x;
  o[i] = (__bf16)W[i];
}

// ---------------------------------------------------------------------------
// prep: (1536,512) fp32 weight -> A-fragment order (f16 pairs), operand-swap.
// A-frag (16x16x32): lane l holds A[row][k], row = l&15, k = ks*32+(l>>4)*8+e.
// Tile (p, mh, g): A rows = g*512 + p*32 + mh*16 + (l&15).
//   dword idx = ((p*2+mh)*48 + g*16 + ks)*256 + l*4 + d ; k = ks*32+(l>>4)*8+2d
// ---------------------------------------------------------------------------
__global__ void prep_bfrag(const float* __restrict__ W, unsigned int* __restrict__ out) {
  int idx = blockIdx.x * 256 + threadIdx.x;   // grid = 393216/256 = 1536
  int p    = idx / 24576;
  int r    = idx % 24576;
  int mh   = r / 12288;
  int r2   = r % 12288;
  int frag = r2 / 256;                        // g*16 + ks
  int lq   = r2 % 256;
  int l    = lq >> 2, d = lq & 3;
  int g    = frag >> 4, ks = frag & 15;
  int row  = g * 512 + p * 32 + mh * 16 + (l & 15);
  int k    = ks * 32 + (l >> 4) * 8 + 2 * d;
  f16x2 pk = { (_Float16)W[(size_t)row * HID + k],
               (_Float16)W[(size_t)row * HID + k + 1] };
  out[idx] = __builtin_bit_cast(unsigned int, pk);
}

// ---------------------------------------------------------------------------
// ip GEMM (verified): C(M,1536)=A(M,512)@Bw(1536,512)^T + bias
// ---------------------------------------------------------------------------
template <typename IPT>
__global__ __launch_bounds__(256) void gemm_ip(
    const float* __restrict__ A, const __bf16* __restrict__ Bw,
    const float* __restrict__ bias, IPT* __restrict__ C) {
  constexpr int K = 512;
  __shared__ __align__(16) __bf16 As[64][72];
  __shared__ __align__(16) __bf16 Bs[64][72];
  const int tid  = threadIdx.x;
  const int bm   = blockIdx.y, bn = blockIdx.x;
  const int lane = tid & 63,  wave = tid >> 6;
  const int wr   = wave >> 1, wc   = wave & 1;
  f32x4 acc[2][2] = {};
  const int r = tid >> 2, q = tid & 3;
  const float*  Arow = A  + (size_t)(bm * 64 + r) * K;
  const __bf16* Brow = Bw + (size_t)(bn * 64 + r) * K;

  for (int k0 = 0; k0 < K; k0 += 64) {
    const float4* as = (const float4*)(Arow + k0);
    #pragma unroll
    for (int i = 0; i < 4; ++i) {
      float4 v = as[q + 4 * i];
      bf16x4 pkt = { (__bf16)v.x, (__bf16)v.y, (__bf16)v.z, (__bf16)v.w };
      *(bf16x4*)&As[r][4 * (q + 4 * i)] = pkt;
    }
    const uint4* bs = (const uint4*)(Brow + k0);
    uint4* bd = (uint4*)&Bs[r][0];
    bd[q]     = bs[q];
    bd[q + 4] = bs[q + 4];
    __syncthreads();

    #pragma unroll
    for (int kk = 0; kk < 64; kk += 32) {
      const int kb = kk + 8 * (lane >> 4);
      bf16x8 a0 = *(const bf16x8*)&As[wr * 32 +      (lane & 15)][kb];
      bf16x8 a1 = *(const bf16x8*)&As[wr * 32 + 16 + (lane & 15)][kb];
      bf16x8 b0 = *(const bf16x8*)&Bs[wc * 32 +      (lane & 15)][kb];
      bf16x8 b1 = *(const bf16x8*)&Bs[wc * 32 + 16 + (lane & 15)][kb];
      acc[0][0] = __builtin_amdgcn_mfma_f32_16x16x32_bf16(a0, b0, acc[0][0], 0, 0, 0);
      acc[0][1] = __builtin_amdgcn_mfma_f32_16x16x32_bf16(a0, b1, acc[0][1], 0, 0, 0);
      acc[1][0] = __builtin_amdgcn_mfma_f32_16x16x32_bf16(a1, b0, acc[1][0], 0, 0, 0);
      acc[1][1] = __builtin_amdgcn_mfma_f32_16x16x32_bf16(a1, b1, acc[1][1], 0, 0, 0);
    }
    __syncthreads();
  }

  const int row0 = bm * 64 + wr * 32 + (lane >> 4) * 4;
  const int col0 = bn * 64 + wc * 32 + (lane & 15);
  #pragma unroll
  for (int fm = 0; fm < 2; ++fm)
    #pragma unroll
    for (int fn = 0; fn < 2; ++fn) {
      int n = col0 + fn * 16;
      float bv = bias[n];
      #pragma unroll
      for (int reg = 0; reg < 4; ++reg) {
        size_t off = (size_t)(row0 + fm * 16 + reg) * G3 + n;
        store_ip<IPT>(C + off, acc[fm][fn][reg] + bv);
      }
    }
}

// ---------------------------------------------------------------------------
// fused recurrence: WG 0..15 layer 0, WG 16..31 layer 1.
// Lane (wave=(mh,set), hi=lane>>4, jj=lane&15) owns batch bb = set*16+jj and
// cols cc0..cc0+3, cc0 = p*32 + mh*16 + hi*4, for all 3 gates.
// Flags: one 64B line per (step, WG):  fl[(t*NWG + p) * FPAD].
// ---------------------------------------------------------------------------
template <typename IPT>
__global__ __launch_bounds__(256, 1) void gru_fused(
    const IPT* __restrict__ ip0,
    const uint4* __restrict__ bfWh0,
    const float* __restrict__ bh0,
    const uint4* __restrict__ bfWh1,
    const uint4* __restrict__ bfWi1,
    const float* __restrict__ bi1,
    const float* __restrict__ bh1,
    float* __restrict__ y1,
    float* __restrict__ hlast,
    unsigned long long* __restrict__ h0buf,   // [2][32][128] 8B (f16 [32][512])
    unsigned long long* __restrict__ h1buf,   // [2][32][128] 8B
    unsigned long long* __restrict__ y0h,     // [S][32][128] 8B
    unsigned int* __restrict__ fl0,           // [S][16][FPAD] (L0-peer copy)
    unsigned int* __restrict__ fl0b,          // [S][16][FPAD] (L1's copy)
    unsigned int* __restrict__ fl1) {         // [S][16][FPAD]
  __shared__ __align__(16) uint4 wiB[6144];   // L1 only (96 KB)
  const int bid = blockIdx.x, tid = threadIdx.x;
  const int lane = tid & 63, wave = tid >> 6;
  const int set = wave & 1, mh = wave >> 1;
  const int jj = lane & 15, hi = lane >> 4;
  const int bb = set * 16 + jj;               // this lane's batch
  const int bbyte = bb * 1024 + hi * 16;      // h B-frag byte base

  if (bid < NWG) {
    // ======================= layer 0 =======================
    const int p = bid;
    const int cc0 = p * 32 + mh * 16 + hi * 4;     // this lane's col base
    uint4 wf[48];
    {
      const uint4* bsrc = bfWh0 + ((size_t)(p * 2 + mh) * 48) * 64 + lane;
      #pragma unroll
      for (int i = 0; i < 48; ++i) wf[i] = bsrc[i * 64];
      #pragma unroll
      for (int i = 0; i < 48; ++i)
        asm volatile("" : "+v"(wf[i].x), "+v"(wf[i].y), "+v"(wf[i].z), "+v"(wf[i].w));
    }
    const float4 bhr4 = *(const float4*)(bh0 + cc0);
    const float4 bhz4 = *(const float4*)(bh0 + 512 + cc0);
    const float4 bhn4 = *(const float4*)(bh0 + 1024 + cc0);
    float hfq[4] = {0.f, 0.f, 0.f, 0.f};

    for (int t = 0; t < S_LEN; ++t) {
      const IPT* bp = ip0 + ((size_t)bb * S_LEN + t) * G3 + cc0;
      float4 ipr = load_ip4<IPT>(bp);
      float4 ipz = load_ip4<IPT>(bp + 512);
      float4 ipn = load_ip4<IPT>(bp + 1024);
      __builtin_amdgcn_sched_barrier(0);

      if (t > 0) {
        const unsigned int* f = fl0 + (size_t)(t - 1) * NWG * FPAD;
        while (true) {
          unsigned v = (lane < NWG)
              ? __hip_atomic_load(f + lane * FPAD, __ATOMIC_RELAXED, __HIP_MEMORY_SCOPE_AGENT)
              : 1u;
          if (__all(v != 0)) break;
          __builtin_amdgcn_s_sleep(1);
        }
      }
      __builtin_amdgcn_sched_barrier(0);

      const char* hb = (const char*)h0buf + (t & 1) * 32768 + bbyte;
      uint4 bf[16];
      #pragma unroll
      for (int ks = 0; ks < 16; ++ks)
        asm volatile("global_load_dwordx4 %0, %1, off offset:%2 sc0 sc1"
                     : "=v"(bf[ks]) : "v"(hb), "i"(ks * 64) : "memory");
      asm volatile("s_waitcnt vmcnt(0)" ::: "memory");
      __builtin_amdgcn_sched_barrier(0);

      f32x4 a0 = {}, a1 = {}, a2 = {};
      #pragma unroll
      for (int ks = 0; ks < 16; ++ks) {
        f16x8 hv = __builtin_bit_cast(f16x8, bf[ks]);
        a0 = __builtin_amdgcn_mfma_f32_16x16x32_f16(__builtin_bit_cast(f16x8, wf[ks]),      hv, a0, 0, 0, 0);
        a1 = __builtin_amdgcn_mfma_f32_16x16x32_f16(__builtin_bit_cast(f16x8, wf[16 + ks]), hv, a1, 0, 0, 0);
        a2 = __builtin_amdgcn_mfma_f32_16x16x32_f16(__builtin_bit_cast(f16x8, wf[32 + ks]), hv, a2, 0, 0, 0);
      }

      unsigned short hx[4];
      #pragma unroll
      for (int q = 0; q < 4; ++q) {
        float rr = sigmoid_f(a0[q] + (&bhr4.x)[q] + (&ipr.x)[q]);
        float zz = sigmoid_f(a1[q] + (&bhz4.x)[q] + (&ipz.x)[q]);
        float nn = tanh_f((&ipn.x)[q] + rr * (a2[q] + (&bhn4.x)[q]));
        float hy = (1.f - zz) * nn + zz * hfq[q];
        hfq[q] = hy;
        hx[q] = __builtin_bit_cast(unsigned short, (_Float16)hy);
      }
      const unsigned long long hw =
          (unsigned long long)hx[0] | ((unsigned long long)hx[1] << 16) |
          ((unsigned long long)hx[2] << 32) | ((unsigned long long)hx[3] << 48);
      const size_t slot = (size_t)bb * 128 + (cc0 >> 2);
      __hip_atomic_store(h0buf + ((size_t)((t + 1) & 1)) * 4096 + slot, hw,
                         __ATOMIC_RELAXED, __HIP_MEMORY_SCOPE_AGENT);
      __hip_atomic_store(y0h + (size_t)t * 4096 + slot, hw,
                         __ATOMIC_RELAXED, __HIP_MEMORY_SCOPE_AGENT);
      asm volatile("s_waitcnt vmcnt(0)" ::: "memory");
      __syncthreads();
      if (tid == 0) {
        const size_t fidx = ((size_t)t * NWG + p) * FPAD;
        __hip_atomic_store(fl0 + fidx, 1u,
                           __ATOMIC_RELAXED, __HIP_MEMORY_SCOPE_AGENT);
        __hip_atomic_store(fl0b + fidx, 1u,
                           __ATOMIC_RELAXED, __HIP_MEMORY_SCOPE_AGENT);
      }
    }
  } else {
    // ======================= layer 1 (shadow ip1) ==========================
    const int p = bid - NWG;
    const int cc0 = p * 32 + mh * 16 + hi * 4;
    uint4 wf[48];
    {
      const uint4* bsrc = bfWh1 + ((size_t)(p * 2 + mh) * 48) * 64 + lane;
      #pragma unroll
      for (int i = 0; i < 48; ++i) wf[i] = bsrc[i * 64];
      #pragma unroll
      for (int i = 0; i < 48; ++i)
        asm volatile("" : "+v"(wf[i].x), "+v"(wf[i].y), "+v"(wf[i].z), "+v"(wf[i].w));
    }
    {
      const uint4* src = bfWi1 + (size_t)p * 6144;
      for (int i = tid; i < 6144; i += 256) wiB[i] = src[i];
    }
    const float4 bir4 = *(const float4*)(bi1 + cc0);
    const float4 biz4 = *(const float4*)(bi1 + 512 + cc0);
    const float4 bin4 = *(const float4*)(bi1 + 1024 + cc0);
    const float4 bhr4 = *(const float4*)(bh1 + cc0);
    const float4 bhz4 = *(const float4*)(bh1 + 512 + cc0);
    const float4 bhn4 = *(const float4*)(bh1 + 1024 + cc0);
    float hfq[4] = {0.f, 0.f, 0.f, 0.f};
    const int wb = mh * 3072 + lane;
    __syncthreads();                          // wiB ready (once)

    // ---- shadow prologue: ip1 for t = 0 ----
    f32x4 i0 = {}, i1 = {}, i2 = {};
    {
      const unsigned int* f = fl0b;           // step 0 flags
      while (true) {
        unsigned v = (lane < NWG)
            ? __hip_atomic_load(f + lane * FPAD, __ATOMIC_RELAXED, __HIP_MEMORY_SCOPE_AGENT)
            : 1u;
        if (__all(v != 0)) break;
        __builtin_amdgcn_s_sleep(1);
      }
      __builtin_amdgcn_sched_barrier(0);
      uint4 ay[16];
      const char* yb = (const char*)y0h + bbyte;
      #pragma unroll
      for (int ks = 0; ks < 16; ++ks)
        asm volatile("global_load_dwordx4 %0, %1, off offset:%2 sc0 sc1"
                     : "=v"(ay[ks]) : "v"(yb), "i"(ks * 64) : "memory");
      asm volatile("s_waitcnt vmcnt(0)" ::: "memory");
      __builtin_amdgcn_sched_barrier(0);
      #pragma unroll
      for (int ks = 0; ks < 16; ++ks) {
        f16x8 yv = __builtin_bit_cast(f16x8, ay[ks]);
        i0 = __builtin_amdgcn_mfma_f32_16x16x32_f16(__builtin_bit_cast(f16x8, wiB[wb + ks * 64]),        yv, i0, 0, 0, 0);
        i1 = __builtin_amdgcn_mfma_f32_16x16x32_f16(__builtin_bit_cast(f16x8, wiB[wb + (16 + ks) * 64]), yv, i1, 0, 0, 0);
        i2 = __builtin_amdgcn_mfma_f32_16x16x32_f16(__builtin_bit_cast(f16x8, wiB[wb + (32 + ks) * 64]), yv, i2, 0, 0, 0);
      }
    }

    for (int t = 0; t < S_LEN; ++t) {
      // -- wait own h1(t-1) --
      if (t > 0) {
        const unsigned int* f = fl1 + (size_t)(t - 1) * NWG * FPAD;
        while (true) {
          unsigned v = (lane < NWG)
              ? __hip_atomic_load(f + lane * FPAD, __ATOMIC_RELAXED, __HIP_MEMORY_SCOPE_AGENT)
              : 1u;
          if (__all(v != 0)) break;
          __builtin_amdgcn_s_sleep(1);
        }
      }
      __builtin_amdgcn_sched_barrier(0);

      uint4 ah[16];
      {
        const char* hb = (const char*)h1buf + (t & 1) * 32768 + bbyte;
        #pragma unroll
        for (int ks = 0; ks < 16; ++ks)
          asm volatile("global_load_dwordx4 %0, %1, off offset:%2 sc0 sc1"
                       : "=v"(ah[ks]) : "v"(hb), "i"(ks * 64) : "memory");
        asm volatile("s_waitcnt vmcnt(0)" ::: "memory");
      }
      __builtin_amdgcn_sched_barrier(0);

      f32x4 c0 = {}, c1 = {}, c2 = {};
      #pragma unroll
      for (int ks = 0; ks < 16; ++ks) {
        f16x8 hv = __builtin_bit_cast(f16x8, ah[ks]);
        c0 = __builtin_amdgcn_mfma_f32_16x16x32_f16(__builtin_bit_cast(f16x8, wf[ks]),      hv, c0, 0, 0, 0);
        c1 = __builtin_amdgcn_mfma_f32_16x16x32_f16(__builtin_bit_cast(f16x8, wf[16 + ks]), hv, c1, 0, 0, 0);
        c2 = __builtin_amdgcn_mfma_f32_16x16x32_f16(__builtin_bit_cast(f16x8, wf[32 + ks]), hv, c2, 0, 0, 0);
      }

      // -- gates in-register (ip1 precomputed); publish h1 (one 8B store) --
      float hyv[4];
      unsigned short hx[4];
      #pragma unroll
      for (int q = 0; q < 4; ++q) {
        float rr = sigmoid_f(i0[q] + c0[q] + (&bir4.x)[q] + (&bhr4.x)[q]);
        float zz = sigmoid_f(i1[q] + c1[q] + (&biz4.x)[q] + (&bhz4.x)[q]);
        float nn = tanh_f((i2[q] + (&bin4.x)[q]) + rr * (c2[q] + (&bhn4.x)[q]));
        float hy = (1.f - zz) * nn + zz * hfq[q];
        hfq[q] = hy;
        hyv[q] = hy;
        hx[q] = __builtin_bit_cast(unsigned short, (_Float16)hy);
      }
      const unsigned long long hw =
          (unsigned long long)hx[0] | ((unsigned long long)hx[1] << 16) |
          ((unsigned long long)hx[2] << 32) | ((unsigned long long)hx[3] << 48);
      __hip_atomic_store(h1buf + ((size_t)((t + 1) & 1)) * 4096 + (size_t)bb * 128 + (cc0 >> 2),
                         hw, __ATOMIC_RELAXED, __HIP_MEMORY_SCOPE_AGENT);
      asm volatile("s_waitcnt vmcnt(0)" ::: "memory");
      __syncthreads();
      if (tid == 0)
        __hip_atomic_store(fl1 + ((size_t)t * NWG + p) * FPAD, 1u,
                           __ATOMIC_RELAXED, __HIP_MEMORY_SCOPE_AGENT);

      // -- y1 float4 store, off the critical path --
      float4 yo = { hyv[0], hyv[1], hyv[2], hyv[3] };
      *(float4*)(y1 + ((size_t)bb * S_LEN + t) * HID + cc0) = yo;
      if (t == S_LEN - 1)
        *(float4*)(hlast + (size_t)bb * HID + cc0) = yo;

      // -- shadow: ip1 for step t+1 (overlaps other L1 WGs' step t) --
      if (t + 1 < S_LEN) {
        const unsigned int* f = fl0b + (size_t)(t + 1) * NWG * FPAD;
        while (true) {
          unsigned v = (lane < NWG)
              ? __hip_atomic_load(f + lane * FPAD, __ATOMIC_RELAXED, __HIP_MEMORY_SCOPE_AGENT)
              : 1u;
          if (__all(v != 0)) break;
          __builtin_amdgcn_s_sleep(1);
        }
        __builtin_amdgcn_sched_barrier(0);
        uint4 ay[16];
        const char* yb = (const char*)y0h + (size_t)(t + 1) * 32768 + bbyte;
        #pragma unroll
        for (int ks = 0; ks < 16; ++ks)
          asm volatile("global_load_dwordx4 %0, %1, off offset:%2 sc0 sc1"
                       : "=v"(ay[ks]) : "v"(yb), "i"(ks * 64) : "memory");
        asm volatile("s_waitcnt vmcnt(0)" ::: "memory");
        __builtin_amdgcn_sched_barrier(0);
        i0 = {}; i1 = {}; i2 = {};
        #pragma unroll
        for (int ks = 0; ks < 16; ++ks) {
          f16x8 yv = __builtin_bit_cast(f16x8, ay[ks]);
          i0 = __builtin_amdgcn_mfma_f32_16x16x32_f16(__builtin_bit_cast(f16x8, wiB[wb + ks * 64]),        yv, i0, 0, 0, 0);
          i1 = __builtin_amdgcn_mfma_f32_16x16x32_f16(__builtin_bit_cast(f16x8, wiB[wb + (16 + ks) * 64]), yv, i1, 0, 0, 0);
          i2 = __builtin_amdgcn_mfma_f32_16x16x32_f16(__builtin_bit_cast(f16x8, wiB[wb + (32 + ks) * 64]), yv, i2, 0, 0, 0);
        }
      }
    }
  }
}

// ---------------------------------------------------------------------------
// ws layout (bytes)
// ---------------------------------------------------------------------------
#define BFWH0_OFF 0ull
#define BFWH1_OFF 1572864ull
#define BFWI1_OFF 3145728ull
#define WI0_OFF   4718592ull
#define H0_OFF    6291456ull      // 65536
#define H1_OFF    6356992ull      // 65536
#define FL0_OFF   6422528ull      // 2097152 ([2048][16][16] dwords)
#define FL0B_OFF  8519680ull      // 2097152
#define FL1_OFF   10616832ull     // 2097152
#define Y0H_OFF   12713984ull     // 67108864
#define IP_OFF    79822848ull

template <typename IPT>
static void run_all(const float* x,
                    const float* Wi0, const float* bi0, const float* Wh0, const float* bh0,
                    const float* Wi1, const float* bi1, const float* Wh1, const float* bh1,
                    float* out, char* ws, hipStream_t stream) {
  unsigned int* bfWh0 = (unsigned int*)(ws + BFWH0_OFF);
  unsigned int* bfWh1 = (unsigned int*)(ws + BFWH1_OFF);
  unsigned int* bfWi1 = (unsigned int*)(ws + BFWI1_OFF);
  __bf16* wi0b = (__bf16*)(ws + WI0_OFF);
  unsigned long long* h0buf = (unsigned long long*)(ws + H0_OFF);
  unsigned long long* h1buf = (unsigned long long*)(ws + H1_OFF);
  unsigned int* fl0  = (unsigned int*)(ws + FL0_OFF);
  unsigned int* fl0b = (unsigned int*)(ws + FL0B_OFF);
  unsigned int* fl1  = (unsigned int*)(ws + FL1_OFF);
  unsigned long long* y0h = (unsigned long long*)(ws + Y0H_OFF);
  IPT* ip = (IPT*)(ws + IP_OFF);
  float* y1    = out;
  float* hlast = out + (size_t)MROWS * HID;

  // zero h bufs + all three padded flag arrays (contiguous region)
  hipMemsetAsync(ws + H0_OFF, 0, 65536ull + 65536ull + 3ull * 2097152ull, stream);

  prep_bfrag<<<dim3(1536), dim3(256), 0, stream>>>(Wh0, bfWh0);
  prep_bfrag<<<dim3(1536), dim3(256), 0, stream>>>(Wh1, bfWh1);
  prep_bfrag<<<dim3(1536), dim3(256), 0, stream>>>(Wi1, bfWi1);
  prep_wib<<<dim3(3072), dim3(256), 0, stream>>>(Wi0, wi0b);

  gemm_ip<IPT><<<dim3(24, 1024), dim3(256), 0, stream>>>(x, wi0b, bi0, ip);
  gru_fused<IPT><<<dim3(2 * NWG), dim3(256), 0, stream>>>(
      ip, (const uint4*)bfWh0, bh0, (const uint4*)bfWh1, (const uint4*)bfWi1,
      bi1, bh1, y1, hlast, h0buf, h1buf, y0h, fl0, fl0b, fl1);
}

extern "C" void kernel_launch(void* const* d_in, const int* in_sizes, int n_in,
                              void* d_out, int out_size, void* d_ws, size_t ws_size,
                              hipStream_t stream) {
  const float* x   = (const float*)d_in[0];
  const float* Wi0 = (const float*)d_in[1];
  const float* bi0 = (const float*)d_in[2];
  const float* Wh0 = (const float*)d_in[3];
  const float* bh0 = (const float*)d_in[4];
  const float* Wi1 = (const float*)d_in[5];
  const float* bi1 = (const float*)d_in[6];
  const float* Wh1 = (const float*)d_in[7];
  const float* bh1 = (const float*)d_in[8];
  float* out = (float*)d_out;
  char*  ws  = (char*)d_ws;

  const size_t need_f32 = IP_OFF + (size_t)MROWS * G3 * 4;
  if (ws_size >= need_f32) {
    run_all<float>(x, Wi0, bi0, Wh0, bh0, Wi1, bi1, Wh1, bh1, out, ws, stream);
  } else {
    run_all<unsigned short>(x, Wi0, bi0, Wh0, bh0, Wi1, bi1, Wh1, bh1, out, ws, stream);
  }
}

// Round 16
// 13547.173 us; speedup vs baseline: 1.0377x; 1.0377x over previous
//
#include <hip/hip_runtime.h>
#include <hip/hip_bf16.h>

// ---------------------------------------------------------------------------
// GRU, 2 layers, B=32, S=2048, D=H=512.
//   gemm:   ip0 = x @ Wi0^T + bi0   (bf16 MFMA)                [verified]
//   fused:  32 WGs. WG 0..15 = layer-0 rec, WG 16..31 = layer-1 rec.
//   r16 = r13 (passing, 13.61 ms) with two bounded trims:
//     (a) L0 single-publish: h0buf dropped; L0 peers read y0h[t-1] directly
//         (same sc0 sc1 loads + flag guard); t=0 skips h-MFMA (h(-1)=0).
//     (b) L1's polls sleep 16 (was 1) — L1 poll storms share LLC with L0's
//         critical path; L1 has ~1 step of slack so coarser polling is free.
//   Everything else byte-for-byte r13. r15's XCD-local scheme hung: sc0-only
//   flags are NOT inter-WG coherent (per-CU L1 may serve stale) — abandoned.
// ---------------------------------------------------------------------------

typedef __bf16    bf16x8 __attribute__((ext_vector_type(8)));
typedef __bf16    bf16x4 __attribute__((ext_vector_type(4)));
typedef float     f32x4  __attribute__((ext_vector_type(4)));
typedef _Float16  f16x2  __attribute__((ext_vector_type(2)));
typedef _Float16  f16x8  __attribute__((ext_vector_type(8)));

#define S_LEN 2048
#define BATCH 32
#define HID   512
#define G3    1536
#define MROWS (BATCH * S_LEN)
#define NWG   16

__device__ inline float sigmoid_f(float x) { return 1.f / (1.f + __expf(-x)); }
__device__ inline float tanh_f(float x) {
  float e = __expf(2.f * x);
  return 1.f - 2.f / (e + 1.f);
}

template <typename IPT>
__device__ inline void store_ip(IPT* p, float v) {
  if constexpr (sizeof(IPT) == 4) *p = v;
  else *p = __builtin_bit_cast(unsigned short, (__bf16)v);
}
template <typename IPT>
__device__ inline float4 load_ip4(const IPT* p) {
  if constexpr (sizeof(IPT) == 4) {
    return *(const float4*)p;
  } else {
    ushort4 u = *(const ushort4*)p;
    float4 r;
    r.x = __uint_as_float((unsigned)u.x << 16);
    r.y = __uint_as_float((unsigned)u.y << 16);
    r.z = __uint_as_float((unsigned)u.z << 16);
    r.w = __uint_as_float((unsigned)u.w << 16);
    return r;
  }
}

// ---------------------------------------------------------------------------
// prep: Wi0 fp32 -> bf16 (for ip GEMM)
// ---------------------------------------------------------------------------
__global__ void prep_wib(const float* __restrict__ W, __bf16* __restrict__ o) {
  int i = blockIdx.x * 256 + threadIdx.x;
  o[i] = (__bf16)W[i];
}

// ---------------------------------------------------------------------------
// prep: (1536,512) fp32 weight -> A-fragment order (f16 pairs), operand-swap.
// A-frag (16x16x32): lane l holds A[row][k], row = l&15, k = ks*32+(l>>4)*8+e.
// Tile (p, mh, g): A rows = g*512 + p*32 + mh*16 + (l&15).
//   dword idx = ((p*2+mh)*48 + g*16 + ks)*256 + l*4 + d ; k = ks*32+(l>>4)*8+2d
// ---------------------------------------------------------------------------
__global__ void prep_bfrag(const float* __restrict__ W, unsigned int* __restrict__ out) {
  int idx = blockIdx.x * 256 + threadIdx.x;   // grid = 393216/256 = 1536
  int p    = idx / 24576;
  int r    = idx % 24576;
  int mh   = r / 12288;
  int r2   = r % 12288;
  int frag = r2 / 256;                        // g*16 + ks
  int lq   = r2 % 256;
  int l    = lq >> 2, d = lq & 3;
  int g    = frag >> 4, ks = frag & 15;
  int row  = g * 512 + p * 32 + mh * 16 + (l & 15);
  int k    = ks * 32 + (l >> 4) * 8 + 2 * d;
  f16x2 pk = { (_Float16)W[(size_t)row * HID + k],
               (_Float16)W[(size_t)row * HID + k + 1] };
  out[idx] = __builtin_bit_cast(unsigned int, pk);
}

// ---------------------------------------------------------------------------
// ip GEMM (verified): C(M,1536)=A(M,512)@Bw(1536,512)^T + bias
// ---------------------------------------------------------------------------
template <typename IPT>
__global__ __launch_bounds__(256) void gemm_ip(
    const float* __restrict__ A, const __bf16* __restrict__ Bw,
    const float* __restrict__ bias, IPT* __restrict__ C) {
  constexpr int K = 512;
  __shared__ __align__(16) __bf16 As[64][72];
  __shared__ __align__(16) __bf16 Bs[64][72];
  const int tid  = threadIdx.x;
  const int bm   = blockIdx.y, bn = blockIdx.x;
  const int lane = tid & 63,  wave = tid >> 6;
  const int wr   = wave >> 1, wc   = wave & 1;
  f32x4 acc[2][2] = {};
  const int r = tid >> 2, q = tid & 3;
  const float*  Arow = A  + (size_t)(bm * 64 + r) * K;
  const __bf16* Brow = Bw + (size_t)(bn * 64 + r) * K;

  for (int k0 = 0; k0 < K; k0 += 64) {
    const float4* as = (const float4*)(Arow + k0);
    #pragma unroll
    for (int i = 0; i < 4; ++i) {
      float4 v = as[q + 4 * i];
      bf16x4 pkt = { (__bf16)v.x, (__bf16)v.y, (__bf16)v.z, (__bf16)v.w };
      *(bf16x4*)&As[r][4 * (q + 4 * i)] = pkt;
    }
    const uint4* bs = (const uint4*)(Brow + k0);
    uint4* bd = (uint4*)&Bs[r][0];
    bd[q]     = bs[q];
    bd[q + 4] = bs[q + 4];
    __syncthreads();

    #pragma unroll
    for (int kk = 0; kk < 64; kk += 32) {
      const int kb = kk + 8 * (lane >> 4);
      bf16x8 a0 = *(const bf16x8*)&As[wr * 32 +      (lane & 15)][kb];
      bf16x8 a1 = *(const bf16x8*)&As[wr * 32 + 16 + (lane & 15)][kb];
      bf16x8 b0 = *(const bf16x8*)&Bs[wc * 32 +      (lane & 15)][kb];
      bf16x8 b1 = *(const bf16x8*)&Bs[wc * 32 + 16 + (lane & 15)][kb];
      acc[0][0] = __builtin_amdgcn_mfma_f32_16x16x32_bf16(a0, b0, acc[0][0], 0, 0, 0);
      acc[0][1] = __builtin_amdgcn_mfma_f32_16x16x32_bf16(a0, b1, acc[0][1], 0, 0, 0);
      acc[1][0] = __builtin_amdgcn_mfma_f32_16x16x32_bf16(a1, b0, acc[1][0], 0, 0, 0);
      acc[1][1] = __builtin_amdgcn_mfma_f32_16x16x32_bf16(a1, b1, acc[1][1], 0, 0, 0);
    }
    __syncthreads();
  }

  const int row0 = bm * 64 + wr * 32 + (lane >> 4) * 4;
  const int col0 = bn * 64 + wc * 32 + (lane & 15);
  #pragma unroll
  for (int fm = 0; fm < 2; ++fm)
    #pragma unroll
    for (int fn = 0; fn < 2; ++fn) {
      int n = col0 + fn * 16;
      float bv = bias[n];
      #pragma unroll
      for (int reg = 0; reg < 4; ++reg) {
        size_t off = (size_t)(row0 + fm * 16 + reg) * G3 + n;
        store_ip<IPT>(C + off, acc[fm][fn][reg] + bv);
      }
    }
}

// ---------------------------------------------------------------------------
// fused recurrence: WG 0..15 layer 0, WG 16..31 layer 1.
// Lane (wave=(mh,set), hi=lane>>4, jj=lane&15) owns batch bb = set*16+jj and
// cols cc0..cc0+3, cc0 = p*32 + mh*16 + hi*4, for all 3 gates.
// ---------------------------------------------------------------------------
template <typename IPT>
__global__ __launch_bounds__(256, 1) void gru_fused(
    const IPT* __restrict__ ip0,
    const uint4* __restrict__ bfWh0,
    const float* __restrict__ bh0,
    const uint4* __restrict__ bfWh1,
    const uint4* __restrict__ bfWi1,
    const float* __restrict__ bi1,
    const float* __restrict__ bh1,
    float* __restrict__ y1,
    float* __restrict__ hlast,
    unsigned long long* __restrict__ h1buf,   // [2][32][128] 8B
    unsigned long long* __restrict__ y0h,     // [S][32][128] 8B (f16 y0 == h0)
    unsigned int* __restrict__ fl0,           // [S][16] per-WG flags
    unsigned int* __restrict__ fl1) {         // [S][16]
  __shared__ __align__(16) uint4 wiB[6144];   // L1 only (96 KB)
  const int bid = blockIdx.x, tid = threadIdx.x;
  const int lane = tid & 63, wave = tid >> 6;
  const int set = wave & 1, mh = wave >> 1;
  const int jj = lane & 15, hi = lane >> 4;
  const int bb = set * 16 + jj;               // this lane's batch
  const int bbyte = bb * 1024 + hi * 16;      // h B-frag byte base

  if (bid < NWG) {
    // ======================= layer 0 (single publish to y0h) ===============
    const int p = bid;
    const int cc0 = p * 32 + mh * 16 + hi * 4;     // this lane's col base
    uint4 wf[48];
    {
      const uint4* bsrc = bfWh0 + ((size_t)(p * 2 + mh) * 48) * 64 + lane;
      #pragma unroll
      for (int i = 0; i < 48; ++i) wf[i] = bsrc[i * 64];
      #pragma unroll
      for (int i = 0; i < 48; ++i)
        asm volatile("" : "+v"(wf[i].x), "+v"(wf[i].y), "+v"(wf[i].z), "+v"(wf[i].w));
    }
    const float4 bhr4 = *(const float4*)(bh0 + cc0);
    const float4 bhz4 = *(const float4*)(bh0 + 512 + cc0);
    const float4 bhn4 = *(const float4*)(bh0 + 1024 + cc0);
    float hfq[4] = {0.f, 0.f, 0.f, 0.f};

    for (int t = 0; t < S_LEN; ++t) {
      const IPT* bp = ip0 + ((size_t)bb * S_LEN + t) * G3 + cc0;
      float4 ipr = load_ip4<IPT>(bp);
      float4 ipz = load_ip4<IPT>(bp + 512);
      float4 ipn = load_ip4<IPT>(bp + 1024);
      __builtin_amdgcn_sched_barrier(0);

      f32x4 a0 = {}, a1 = {}, a2 = {};
      if (t > 0) {
        const unsigned int* f = fl0 + (size_t)(t - 1) * NWG;
        while (true) {
          unsigned v = (lane < NWG)
              ? __hip_atomic_load(f + lane, __ATOMIC_RELAXED, __HIP_MEMORY_SCOPE_AGENT)
              : 1u;
          if (__all(v != 0)) break;
          __builtin_amdgcn_s_sleep(1);
        }
        __builtin_amdgcn_sched_barrier(0);

        // h(t-1) B-fragments straight from y0h[t-1] (flag-guarded)
        const char* hb = (const char*)y0h + (size_t)(t - 1) * 32768 + bbyte;
        uint4 bf[16];
        #pragma unroll
        for (int ks = 0; ks < 16; ++ks)
          asm volatile("global_load_dwordx4 %0, %1, off offset:%2 sc0 sc1"
                       : "=v"(bf[ks]) : "v"(hb), "i"(ks * 64) : "memory");
        asm volatile("s_waitcnt vmcnt(0)" ::: "memory");
        __builtin_amdgcn_sched_barrier(0);

        #pragma unroll
        for (int ks = 0; ks < 16; ++ks) {
          f16x8 hv = __builtin_bit_cast(f16x8, bf[ks]);
          a0 = __builtin_amdgcn_mfma_f32_16x16x32_f16(__builtin_bit_cast(f16x8, wf[ks]),      hv, a0, 0, 0, 0);
          a1 = __builtin_amdgcn_mfma_f32_16x16x32_f16(__builtin_bit_cast(f16x8, wf[16 + ks]), hv, a1, 0, 0, 0);
          a2 = __builtin_amdgcn_mfma_f32_16x16x32_f16(__builtin_bit_cast(f16x8, wf[32 + ks]), hv, a2, 0, 0, 0);
        }
      }

      unsigned short hx[4];
      #pragma unroll
      for (int q = 0; q < 4; ++q) {
        float rr = sigmoid_f(a0[q] + (&bhr4.x)[q] + (&ipr.x)[q]);
        float zz = sigmoid_f(a1[q] + (&bhz4.x)[q] + (&ipz.x)[q]);
        float nn = tanh_f((&ipn.x)[q] + rr * (a2[q] + (&bhn4.x)[q]));
        float hy = (1.f - zz) * nn + zz * hfq[q];
        hfq[q] = hy;
        hx[q] = __builtin_bit_cast(unsigned short, (_Float16)hy);
      }
      const unsigned long long hw =
          (unsigned long long)hx[0] | ((unsigned long long)hx[1] << 16) |
          ((unsigned long long)hx[2] << 32) | ((unsigned long long)hx[3] << 48);
      __hip_atomic_store(y0h + (size_t)t * 4096 + (size_t)bb * 128 + (cc0 >> 2), hw,
                         __ATOMIC_RELAXED, __HIP_MEMORY_SCOPE_AGENT);
      asm volatile("s_waitcnt vmcnt(0)" ::: "memory");
      __syncthreads();
      if (tid == 0)
        __hip_atomic_store(fl0 + (size_t)t * NWG + p, 1u,
                           __ATOMIC_RELAXED, __HIP_MEMORY_SCOPE_AGENT);
    }
  } else {
    // ======================= layer 1 (shadow ip1) ==========================
    const int p = bid - NWG;
    const int cc0 = p * 32 + mh * 16 + hi * 4;
    uint4 wf[48];
    {
      const uint4* bsrc = bfWh1 + ((size_t)(p * 2 + mh) * 48) * 64 + lane;
      #pragma unroll
      for (int i = 0; i < 48; ++i) wf[i] = bsrc[i * 64];
      #pragma unroll
      for (int i = 0; i < 48; ++i)
        asm volatile("" : "+v"(wf[i].x), "+v"(wf[i].y), "+v"(wf[i].z), "+v"(wf[i].w));
    }
    {
      const uint4* src = bfWi1 + (size_t)p * 6144;
      for (int i = tid; i < 6144; i += 256) wiB[i] = src[i];
    }
    const float4 bir4 = *(const float4*)(bi1 + cc0);
    const float4 biz4 = *(const float4*)(bi1 + 512 + cc0);
    const float4 bin4 = *(const float4*)(bi1 + 1024 + cc0);
    const float4 bhr4 = *(const float4*)(bh1 + cc0);
    const float4 bhz4 = *(const float4*)(bh1 + 512 + cc0);
    const float4 bhn4 = *(const float4*)(bh1 + 1024 + cc0);
    float hfq[4] = {0.f, 0.f, 0.f, 0.f};
    const int wb = mh * 3072 + lane;
    __syncthreads();                          // wiB ready (once)

    // ---- shadow prologue: ip1 for t = 0 ----
    f32x4 i0 = {}, i1 = {}, i2 = {};
    {
      const unsigned int* f = fl0;            // fl0[0]
      while (true) {
        unsigned v = (lane < NWG)
            ? __hip_atomic_load(f + lane, __ATOMIC_RELAXED, __HIP_MEMORY_SCOPE_AGENT)
            : 1u;
        if (__all(v != 0)) break;
        __builtin_amdgcn_s_sleep(16);
      }
      __builtin_amdgcn_sched_barrier(0);
      uint4 ay[16];
      const char* yb = (const char*)y0h + bbyte;
      #pragma unroll
      for (int ks = 0; ks < 16; ++ks)
        asm volatile("global_load_dwordx4 %0, %1, off offset:%2 sc0 sc1"
                     : "=v"(ay[ks]) : "v"(yb), "i"(ks * 64) : "memory");
      asm volatile("s_waitcnt vmcnt(0)" ::: "memory");
      __builtin_amdgcn_sched_barrier(0);
      #pragma unroll
      for (int ks = 0; ks < 16; ++ks) {
        f16x8 yv = __builtin_bit_cast(f16x8, ay[ks]);
        i0 = __builtin_amdgcn_mfma_f32_16x16x32_f16(__builtin_bit_cast(f16x8, wiB[wb + ks * 64]),        yv, i0, 0, 0, 0);
        i1 = __builtin_amdgcn_mfma_f32_16x16x32_f16(__builtin_bit_cast(f16x8, wiB[wb + (16 + ks) * 64]), yv, i1, 0, 0, 0);
        i2 = __builtin_amdgcn_mfma_f32_16x16x32_f16(__builtin_bit_cast(f16x8, wiB[wb + (32 + ks) * 64]), yv, i2, 0, 0, 0);
      }
    }

    for (int t = 0; t < S_LEN; ++t) {
      // -- wait own h1(t-1) --
      if (t > 0) {
        const unsigned int* f = fl1 + (size_t)(t - 1) * NWG;
        while (true) {
          unsigned v = (lane < NWG)
              ? __hip_atomic_load(f + lane, __ATOMIC_RELAXED, __HIP_MEMORY_SCOPE_AGENT)
              : 1u;
          if (__all(v != 0)) break;
          __builtin_amdgcn_s_sleep(16);
        }
      }
      __builtin_amdgcn_sched_barrier(0);

      uint4 ah[16];
      {
        const char* hb = (const char*)h1buf + (t & 1) * 32768 + bbyte;
        #pragma unroll
        for (int ks = 0; ks < 16; ++ks)
          asm volatile("global_load_dwordx4 %0, %1, off offset:%2 sc0 sc1"
                       : "=v"(ah[ks]) : "v"(hb), "i"(ks * 64) : "memory");
        asm volatile("s_waitcnt vmcnt(0)" ::: "memory");
      }
      __builtin_amdgcn_sched_barrier(0);

      f32x4 c0 = {}, c1 = {}, c2 = {};
      #pragma unroll
      for (int ks = 0; ks < 16; ++ks) {
        f16x8 hv = __builtin_bit_cast(f16x8, ah[ks]);
        c0 = __builtin_amdgcn_mfma_f32_16x16x32_f16(__builtin_bit_cast(f16x8, wf[ks]),      hv, c0, 0, 0, 0);
        c1 = __builtin_amdgcn_mfma_f32_16x16x32_f16(__builtin_bit_cast(f16x8, wf[16 + ks]), hv, c1, 0, 0, 0);
        c2 = __builtin_amdgcn_mfma_f32_16x16x32_f16(__builtin_bit_cast(f16x8, wf[32 + ks]), hv, c2, 0, 0, 0);
      }

      // -- gates in-register (ip1 precomputed); publish h1 (one 8B store) --
      float hyv[4];
      unsigned short hx[4];
      #pragma unroll
      for (int q = 0; q < 4; ++q) {
        float rr = sigmoid_f(i0[q] + c0[q] + (&bir4.x)[q] + (&bhr4.x)[q]);
        float zz = sigmoid_f(i1[q] + c1[q] + (&biz4.x)[q] + (&bhz4.x)[q]);
        float nn = tanh_f((i2[q] + (&bin4.x)[q]) + rr * (c2[q] + (&bhn4.x)[q]));
        float hy = (1.f - zz) * nn + zz * hfq[q];
        hfq[q] = hy;
        hyv[q] = hy;
        hx[q] = __builtin_bit_cast(unsigned short, (_Float16)hy);
      }
      const unsigned long long hw =
          (unsigned long long)hx[0] | ((unsigned long long)hx[1] << 16) |
          ((unsigned long long)hx[2] << 32) | ((unsigned long long)hx[3] << 48);
      __hip_atomic_store(h1buf + ((size_t)((t + 1) & 1)) * 4096 + (size_t)bb * 128 + (cc0 >> 2),
                         hw, __ATOMIC_RELAXED, __HIP_MEMORY_SCOPE_AGENT);
      asm volatile("s_waitcnt vmcnt(0)" ::: "memory");
      __syncthreads();
      if (tid == 0)
        __hip_atomic_store(fl1 + (size_t)t * NWG + p, 1u,
                           __ATOMIC_RELAXED, __HIP_MEMORY_SCOPE_AGENT);

      // -- y1 float4 store, off the critical path --
      float4 yo = { hyv[0], hyv[1], hyv[2], hyv[3] };
      *(float4*)(y1 + ((size_t)bb * S_LEN + t) * HID + cc0) = yo;
      if (t == S_LEN - 1)
        *(float4*)(hlast + (size_t)bb * HID + cc0) = yo;

      // -- shadow: ip1 for step t+1 (overlaps other L1 WGs' step t) --
      if (t + 1 < S_LEN) {
        const unsigned int* f = fl0 + (size_t)(t + 1) * NWG;
        while (true) {
          unsigned v = (lane < NWG)
              ? __hip_atomic_load(f + lane, __ATOMIC_RELAXED, __HIP_MEMORY_SCOPE_AGENT)
              : 1u;
          if (__all(v != 0)) break;
          __builtin_amdgcn_s_sleep(16);
        }
        __builtin_amdgcn_sched_barrier(0);
        uint4 ay[16];
        const char* yb = (const char*)y0h + (size_t)(t + 1) * 32768 + bbyte;
        #pragma unroll
        for (int ks = 0; ks < 16; ++ks)
          asm volatile("global_load_dwordx4 %0, %1, off offset:%2 sc0 sc1"
                       : "=v"(ay[ks]) : "v"(yb), "i"(ks * 64) : "memory");
        asm volatile("s_waitcnt vmcnt(0)" ::: "memory");
        __builtin_amdgcn_sched_barrier(0);
        i0 = {}; i1 = {}; i2 = {};
        #pragma unroll
        for (int ks = 0; ks < 16; ++ks) {
          f16x8 yv = __builtin_bit_cast(f16x8, ay[ks]);
          i0 = __builtin_amdgcn_mfma_f32_16x16x32_f16(__builtin_bit_cast(f16x8, wiB[wb + ks * 64]),        yv, i0, 0, 0, 0);
          i1 = __builtin_amdgcn_mfma_f32_16x16x32_f16(__builtin_bit_cast(f16x8, wiB[wb + (16 + ks) * 64]), yv, i1, 0, 0, 0);
          i2 = __builtin_amdgcn_mfma_f32_16x16x32_f16(__builtin_bit_cast(f16x8, wiB[wb + (32 + ks) * 64]), yv, i2, 0, 0, 0);
        }
      }
    }
  }
}

// ---------------------------------------------------------------------------
// ws layout (bytes)
// ---------------------------------------------------------------------------
#define BFWH0_OFF 0ull
#define BFWH1_OFF 1572864ull
#define BFWI1_OFF 3145728ull
#define WI0_OFF   4718592ull
#define H1_OFF    6291456ull      // 65536
#define FL0_OFF   6356992ull      // 131072 ([2048][16] dwords)
#define FL1_OFF   6488064ull      // 131072
#define Y0H_OFF   6619136ull      // 67108864
#define IP_OFF    73728000ull

template <typename IPT>
static void run_all(const float* x,
                    const float* Wi0, const float* bi0, const float* Wh0, const float* bh0,
                    const float* Wi1, const float* bi1, const float* Wh1, const float* bh1,
                    float* out, char* ws, hipStream_t stream) {
  unsigned int* bfWh0 = (unsigned int*)(ws + BFWH0_OFF);
  unsigned int* bfWh1 = (unsigned int*)(ws + BFWH1_OFF);
  unsigned int* bfWi1 = (unsigned int*)(ws + BFWI1_OFF);
  __bf16* wi0b = (__bf16*)(ws + WI0_OFF);
  unsigned long long* h1buf = (unsigned long long*)(ws + H1_OFF);
  unsigned int* fl0 = (unsigned int*)(ws + FL0_OFF);
  unsigned int* fl1 = (unsigned int*)(ws + FL1_OFF);
  unsigned long long* y0h = (unsigned long long*)(ws + Y0H_OFF);
  IPT* ip = (IPT*)(ws + IP_OFF);
  float* y1    = out;
  float* hlast = out + (size_t)MROWS * HID;

  // zero h1 double-buffer + both flag arrays (contiguous region) each launch
  hipMemsetAsync(ws + H1_OFF, 0, 65536 + 131072 + 131072, stream);

  prep_bfrag<<<dim3(1536), dim3(256), 0, stream>>>(Wh0, bfWh0);
  prep_bfrag<<<dim3(1536), dim3(256), 0, stream>>>(Wh1, bfWh1);
  prep_bfrag<<<dim3(1536), dim3(256), 0, stream>>>(Wi1, bfWi1);
  prep_wib<<<dim3(3072), dim3(256), 0, stream>>>(Wi0, wi0b);

  gemm_ip<IPT><<<dim3(24, 1024), dim3(256), 0, stream>>>(x, wi0b, bi0, ip);
  gru_fused<IPT><<<dim3(2 * NWG), dim3(256), 0, stream>>>(
      ip, (const uint4*)bfWh0, bh0, (const uint4*)bfWh1, (const uint4*)bfWi1,
      bi1, bh1, y1, hlast, h1buf, y0h, fl0, fl1);
}

extern "C" void kernel_launch(void* const* d_in, const int* in_sizes, int n_in,
                              void* d_out, int out_size, void* d_ws, size_t ws_size,
                              hipStream_t stream) {
  const float* x   = (const float*)d_in[0];
  const float* Wi0 = (const float*)d_in[1];
  const float* bi0 = (const float*)d_in[2];
  const float* Wh0 = (const float*)d_in[3];
  const float* bh0 = (const float*)d_in[4];
  const float* Wi1 = (const float*)d_in[5];
  const float* bi1 = (const float*)d_in[6];
  const float* Wh1 = (const float*)d_in[7];
  const float* bh1 = (const float*)d_in[8];
  float* out = (float*)d_out;
  char*  ws  = (char*)d_ws;

  const size_t need_f32 = IP_OFF + (size_t)MROWS * G3 * 4;
  if (ws_size >= need_f32) {
    run_all<float>(x, Wi0, bi0, Wh0, bh0, Wi1, bi1, Wh1, bh1, out, ws, stream);
  } else {
    run_all<unsigned short>(x, Wi0, bi0, Wh0, bh0, Wi1, bi1, Wh1, bh1, out, ws, stream);
  }
}

// Round 17
// 12399.899 us; speedup vs baseline: 1.1337x; 1.0925x over previous
//
#include <hip/hip_runtime.h>
#include <hip/hip_bf16.h>

// ---------------------------------------------------------------------------
// GRU, 2 layers, B=32, S=2048, D=H=512.
//   gemm:   ip0 = x @ Wi0^T + bi0   (bf16 MFMA)                [verified]
//   fused:  32 WGs. WG 0..15 = layer-0 rec, WG 16..31 = layer-1 rec.
//   r17 = r16 (passing, 13.55 ms) + ONE change: PER-WAVE flags.
//     Waves write disjoint 8B slots, so each wave certifies its own stores:
//     wave-local vmcnt(0) drain -> lane0 stores fl[t][p*4+wave]. No
//     __syncthreads in the loops (was only there so tid0's flag covered all
//     waves). Consumers poll 64 flags with 64 lanes (1 flag/lane). Removes
//     the per-step intra-WG straggler barrier from the serial chain.
//   Everything else byte-for-byte r16.
// ---------------------------------------------------------------------------

typedef __bf16    bf16x8 __attribute__((ext_vector_type(8)));
typedef __bf16    bf16x4 __attribute__((ext_vector_type(4)));
typedef float     f32x4  __attribute__((ext_vector_type(4)));
typedef _Float16  f16x2  __attribute__((ext_vector_type(2)));
typedef _Float16  f16x8  __attribute__((ext_vector_type(8)));

#define S_LEN 2048
#define BATCH 32
#define HID   512
#define G3    1536
#define MROWS (BATCH * S_LEN)
#define NWG   16
#define NFL   64                 // flags per step (per wave)

__device__ inline float sigmoid_f(float x) { return 1.f / (1.f + __expf(-x)); }
__device__ inline float tanh_f(float x) {
  float e = __expf(2.f * x);
  return 1.f - 2.f / (e + 1.f);
}

template <typename IPT>
__device__ inline void store_ip(IPT* p, float v) {
  if constexpr (sizeof(IPT) == 4) *p = v;
  else *p = __builtin_bit_cast(unsigned short, (__bf16)v);
}
template <typename IPT>
__device__ inline float4 load_ip4(const IPT* p) {
  if constexpr (sizeof(IPT) == 4) {
    return *(const float4*)p;
  } else {
    ushort4 u = *(const ushort4*)p;
    float4 r;
    r.x = __uint_as_float((unsigned)u.x << 16);
    r.y = __uint_as_float((unsigned)u.y << 16);
    r.z = __uint_as_float((unsigned)u.z << 16);
    r.w = __uint_as_float((unsigned)u.w << 16);
    return r;
  }
}

// ---------------------------------------------------------------------------
// prep: Wi0 fp32 -> bf16 (for ip GEMM)
// ---------------------------------------------------------------------------
__global__ void prep_wib(const float* __restrict__ W, __bf16* __restrict__ o) {
  int i = blockIdx.x * 256 + threadIdx.x;
  o[i] = (__bf16)W[i];
}

// ---------------------------------------------------------------------------
// prep: (1536,512) fp32 weight -> A-fragment order (f16 pairs), operand-swap.
// A-frag (16x16x32): lane l holds A[row][k], row = l&15, k = ks*32+(l>>4)*8+e.
// Tile (p, mh, g): A rows = g*512 + p*32 + mh*16 + (l&15).
//   dword idx = ((p*2+mh)*48 + g*16 + ks)*256 + l*4 + d ; k = ks*32+(l>>4)*8+2d
// ---------------------------------------------------------------------------
__global__ void prep_bfrag(const float* __restrict__ W, unsigned int* __restrict__ out) {
  int idx = blockIdx.x * 256 + threadIdx.x;   // grid = 393216/256 = 1536
  int p    = idx / 24576;
  int r    = idx % 24576;
  int mh   = r / 12288;
  int r2   = r % 12288;
  int frag = r2 / 256;                        // g*16 + ks
  int lq   = r2 % 256;
  int l    = lq >> 2, d = lq & 3;
  int g    = frag >> 4, ks = frag & 15;
  int row  = g * 512 + p * 32 + mh * 16 + (l & 15);
  int k    = ks * 32 + (l >> 4) * 8 + 2 * d;
  f16x2 pk = { (_Float16)W[(size_t)row * HID + k],
               (_Float16)W[(size_t)row * HID + k + 1] };
  out[idx] = __builtin_bit_cast(unsigned int, pk);
}

// ---------------------------------------------------------------------------
// ip GEMM (verified): C(M,1536)=A(M,512)@Bw(1536,512)^T + bias
// ---------------------------------------------------------------------------
template <typename IPT>
__global__ __launch_bounds__(256) void gemm_ip(
    const float* __restrict__ A, const __bf16* __restrict__ Bw,
    const float* __restrict__ bias, IPT* __restrict__ C) {
  constexpr int K = 512;
  __shared__ __align__(16) __bf16 As[64][72];
  __shared__ __align__(16) __bf16 Bs[64][72];
  const int tid  = threadIdx.x;
  const int bm   = blockIdx.y, bn = blockIdx.x;
  const int lane = tid & 63,  wave = tid >> 6;
  const int wr   = wave >> 1, wc   = wave & 1;
  f32x4 acc[2][2] = {};
  const int r = tid >> 2, q = tid & 3;
  const float*  Arow = A  + (size_t)(bm * 64 + r) * K;
  const __bf16* Brow = Bw + (size_t)(bn * 64 + r) * K;

  for (int k0 = 0; k0 < K; k0 += 64) {
    const float4* as = (const float4*)(Arow + k0);
    #pragma unroll
    for (int i = 0; i < 4; ++i) {
      float4 v = as[q + 4 * i];
      bf16x4 pkt = { (__bf16)v.x, (__bf16)v.y, (__bf16)v.z, (__bf16)v.w };
      *(bf16x4*)&As[r][4 * (q + 4 * i)] = pkt;
    }
    const uint4* bs = (const uint4*)(Brow + k0);
    uint4* bd = (uint4*)&Bs[r][0];
    bd[q]     = bs[q];
    bd[q + 4] = bs[q + 4];
    __syncthreads();

    #pragma unroll
    for (int kk = 0; kk < 64; kk += 32) {
      const int kb = kk + 8 * (lane >> 4);
      bf16x8 a0 = *(const bf16x8*)&As[wr * 32 +      (lane & 15)][kb];
      bf16x8 a1 = *(const bf16x8*)&As[wr * 32 + 16 + (lane & 15)][kb];
      bf16x8 b0 = *(const bf16x8*)&Bs[wc * 32 +      (lane & 15)][kb];
      bf16x8 b1 = *(const bf16x8*)&Bs[wc * 32 + 16 + (lane & 15)][kb];
      acc[0][0] = __builtin_amdgcn_mfma_f32_16x16x32_bf16(a0, b0, acc[0][0], 0, 0, 0);
      acc[0][1] = __builtin_amdgcn_mfma_f32_16x16x32_bf16(a0, b1, acc[0][1], 0, 0, 0);
      acc[1][0] = __builtin_amdgcn_mfma_f32_16x16x32_bf16(a1, b0, acc[1][0], 0, 0, 0);
      acc[1][1] = __builtin_amdgcn_mfma_f32_16x16x32_bf16(a1, b1, acc[1][1], 0, 0, 0);
    }
    __syncthreads();
  }

  const int row0 = bm * 64 + wr * 32 + (lane >> 4) * 4;
  const int col0 = bn * 64 + wc * 32 + (lane & 15);
  #pragma unroll
  for (int fm = 0; fm < 2; ++fm)
    #pragma unroll
    for (int fn = 0; fn < 2; ++fn) {
      int n = col0 + fn * 16;
      float bv = bias[n];
      #pragma unroll
      for (int reg = 0; reg < 4; ++reg) {
        size_t off = (size_t)(row0 + fm * 16 + reg) * G3 + n;
        store_ip<IPT>(C + off, acc[fm][fn][reg] + bv);
      }
    }
}

// ---------------------------------------------------------------------------
// fused recurrence: WG 0..15 layer 0, WG 16..31 layer 1.
// Lane (wave=(mh,set), hi=lane>>4, jj=lane&15) owns batch bb = set*16+jj and
// cols cc0..cc0+3, cc0 = p*32 + mh*16 + hi*4, for all 3 gates.
// Flags: PER-WAVE, fl[t][p*4 + wave]; consumers poll 64 with 64 lanes.
// ---------------------------------------------------------------------------
template <typename IPT>
__global__ __launch_bounds__(256, 1) void gru_fused(
    const IPT* __restrict__ ip0,
    const uint4* __restrict__ bfWh0,
    const float* __restrict__ bh0,
    const uint4* __restrict__ bfWh1,
    const uint4* __restrict__ bfWi1,
    const float* __restrict__ bi1,
    const float* __restrict__ bh1,
    float* __restrict__ y1,
    float* __restrict__ hlast,
    unsigned long long* __restrict__ h1buf,   // [2][32][128] 8B
    unsigned long long* __restrict__ y0h,     // [S][32][128] 8B (f16 y0 == h0)
    unsigned int* __restrict__ fl0,           // [S][64] per-wave flags
    unsigned int* __restrict__ fl1) {         // [S][64]
  __shared__ __align__(16) uint4 wiB[6144];   // L1 only (96 KB)
  const int bid = blockIdx.x, tid = threadIdx.x;
  const int lane = tid & 63, wave = tid >> 6;
  const int set = wave & 1, mh = wave >> 1;
  const int jj = lane & 15, hi = lane >> 4;
  const int bb = set * 16 + jj;               // this lane's batch
  const int bbyte = bb * 1024 + hi * 16;      // h B-frag byte base

  if (bid < NWG) {
    // ======================= layer 0 (single publish to y0h) ===============
    const int p = bid;
    const int cc0 = p * 32 + mh * 16 + hi * 4;     // this lane's col base
    uint4 wf[48];
    {
      const uint4* bsrc = bfWh0 + ((size_t)(p * 2 + mh) * 48) * 64 + lane;
      #pragma unroll
      for (int i = 0; i < 48; ++i) wf[i] = bsrc[i * 64];
      #pragma unroll
      for (int i = 0; i < 48; ++i)
        asm volatile("" : "+v"(wf[i].x), "+v"(wf[i].y), "+v"(wf[i].z), "+v"(wf[i].w));
    }
    const float4 bhr4 = *(const float4*)(bh0 + cc0);
    const float4 bhz4 = *(const float4*)(bh0 + 512 + cc0);
    const float4 bhn4 = *(const float4*)(bh0 + 1024 + cc0);
    float hfq[4] = {0.f, 0.f, 0.f, 0.f};

    for (int t = 0; t < S_LEN; ++t) {
      const IPT* bp = ip0 + ((size_t)bb * S_LEN + t) * G3 + cc0;
      float4 ipr = load_ip4<IPT>(bp);
      float4 ipz = load_ip4<IPT>(bp + 512);
      float4 ipn = load_ip4<IPT>(bp + 1024);
      __builtin_amdgcn_sched_barrier(0);

      f32x4 a0 = {}, a1 = {}, a2 = {};
      if (t > 0) {
        const unsigned int* f = fl0 + (size_t)(t - 1) * NFL;
        while (true) {
          unsigned v = __hip_atomic_load(f + lane, __ATOMIC_RELAXED,
                                         __HIP_MEMORY_SCOPE_AGENT);
          if (__all(v != 0)) break;
          __builtin_amdgcn_s_sleep(1);
        }
        __builtin_amdgcn_sched_barrier(0);

        // h(t-1) B-fragments straight from y0h[t-1] (flag-guarded)
        const char* hb = (const char*)y0h + (size_t)(t - 1) * 32768 + bbyte;
        uint4 bf[16];
        #pragma unroll
        for (int ks = 0; ks < 16; ++ks)
          asm volatile("global_load_dwordx4 %0, %1, off offset:%2 sc0 sc1"
                       : "=v"(bf[ks]) : "v"(hb), "i"(ks * 64) : "memory");
        asm volatile("s_waitcnt vmcnt(0)" ::: "memory");
        __builtin_amdgcn_sched_barrier(0);

        #pragma unroll
        for (int ks = 0; ks < 16; ++ks) {
          f16x8 hv = __builtin_bit_cast(f16x8, bf[ks]);
          a0 = __builtin_amdgcn_mfma_f32_16x16x32_f16(__builtin_bit_cast(f16x8, wf[ks]),      hv, a0, 0, 0, 0);
          a1 = __builtin_amdgcn_mfma_f32_16x16x32_f16(__builtin_bit_cast(f16x8, wf[16 + ks]), hv, a1, 0, 0, 0);
          a2 = __builtin_amdgcn_mfma_f32_16x16x32_f16(__builtin_bit_cast(f16x8, wf[32 + ks]), hv, a2, 0, 0, 0);
        }
      }

      unsigned short hx[4];
      #pragma unroll
      for (int q = 0; q < 4; ++q) {
        float rr = sigmoid_f(a0[q] + (&bhr4.x)[q] + (&ipr.x)[q]);
        float zz = sigmoid_f(a1[q] + (&bhz4.x)[q] + (&ipz.x)[q]);
        float nn = tanh_f((&ipn.x)[q] + rr * (a2[q] + (&bhn4.x)[q]));
        float hy = (1.f - zz) * nn + zz * hfq[q];
        hfq[q] = hy;
        hx[q] = __builtin_bit_cast(unsigned short, (_Float16)hy);
      }
      const unsigned long long hw =
          (unsigned long long)hx[0] | ((unsigned long long)hx[1] << 16) |
          ((unsigned long long)hx[2] << 32) | ((unsigned long long)hx[3] << 48);
      __hip_atomic_store(y0h + (size_t)t * 4096 + (size_t)bb * 128 + (cc0 >> 2), hw,
                         __ATOMIC_RELAXED, __HIP_MEMORY_SCOPE_AGENT);
      // wave-local drain, then this wave's flag (no barrier)
      asm volatile("s_waitcnt vmcnt(0)" ::: "memory");
      if (lane == 0)
        __hip_atomic_store(fl0 + (size_t)t * NFL + p * 4 + wave, 1u,
                           __ATOMIC_RELAXED, __HIP_MEMORY_SCOPE_AGENT);
    }
  } else {
    // ======================= layer 1 (shadow ip1) ==========================
    const int p = bid - NWG;
    const int cc0 = p * 32 + mh * 16 + hi * 4;
    uint4 wf[48];
    {
      const uint4* bsrc = bfWh1 + ((size_t)(p * 2 + mh) * 48) * 64 + lane;
      #pragma unroll
      for (int i = 0; i < 48; ++i) wf[i] = bsrc[i * 64];
      #pragma unroll
      for (int i = 0; i < 48; ++i)
        asm volatile("" : "+v"(wf[i].x), "+v"(wf[i].y), "+v"(wf[i].z), "+v"(wf[i].w));
    }
    {
      const uint4* src = bfWi1 + (size_t)p * 6144;
      for (int i = tid; i < 6144; i += 256) wiB[i] = src[i];
    }
    const float4 bir4 = *(const float4*)(bi1 + cc0);
    const float4 biz4 = *(const float4*)(bi1 + 512 + cc0);
    const float4 bin4 = *(const float4*)(bi1 + 1024 + cc0);
    const float4 bhr4 = *(const float4*)(bh1 + cc0);
    const float4 bhz4 = *(const float4*)(bh1 + 512 + cc0);
    const float4 bhn4 = *(const float4*)(bh1 + 1024 + cc0);
    float hfq[4] = {0.f, 0.f, 0.f, 0.f};
    const int wb = mh * 3072 + lane;
    __syncthreads();                          // wiB ready (once, before loop)

    // ---- shadow prologue: ip1 for t = 0 ----
    f32x4 i0 = {}, i1 = {}, i2 = {};
    {
      const unsigned int* f = fl0;            // fl0[0]
      while (true) {
        unsigned v = __hip_atomic_load(f + lane, __ATOMIC_RELAXED,
                                       __HIP_MEMORY_SCOPE_AGENT);
        if (__all(v != 0)) break;
        __builtin_amdgcn_s_sleep(16);
      }
      __builtin_amdgcn_sched_barrier(0);
      uint4 ay[16];
      const char* yb = (const char*)y0h + bbyte;
      #pragma unroll
      for (int ks = 0; ks < 16; ++ks)
        asm volatile("global_load_dwordx4 %0, %1, off offset:%2 sc0 sc1"
                     : "=v"(ay[ks]) : "v"(yb), "i"(ks * 64) : "memory");
      asm volatile("s_waitcnt vmcnt(0)" ::: "memory");
      __builtin_amdgcn_sched_barrier(0);
      #pragma unroll
      for (int ks = 0; ks < 16; ++ks) {
        f16x8 yv = __builtin_bit_cast(f16x8, ay[ks]);
        i0 = __builtin_amdgcn_mfma_f32_16x16x32_f16(__builtin_bit_cast(f16x8, wiB[wb + ks * 64]),        yv, i0, 0, 0, 0);
        i1 = __builtin_amdgcn_mfma_f32_16x16x32_f16(__builtin_bit_cast(f16x8, wiB[wb + (16 + ks) * 64]), yv, i1, 0, 0, 0);
        i2 = __builtin_amdgcn_mfma_f32_16x16x32_f16(__builtin_bit_cast(f16x8, wiB[wb + (32 + ks) * 64]), yv, i2, 0, 0, 0);
      }
    }

    for (int t = 0; t < S_LEN; ++t) {
      // -- wait own h1(t-1) --
      if (t > 0) {
        const unsigned int* f = fl1 + (size_t)(t - 1) * NFL;
        while (true) {
          unsigned v = __hip_atomic_load(f + lane, __ATOMIC_RELAXED,
                                         __HIP_MEMORY_SCOPE_AGENT);
          if (__all(v != 0)) break;
          __builtin_amdgcn_s_sleep(16);
        }
      }
      __builtin_amdgcn_sched_barrier(0);

      uint4 ah[16];
      {
        const char* hb = (const char*)h1buf + (t & 1) * 32768 + bbyte;
        #pragma unroll
        for (int ks = 0; ks < 16; ++ks)
          asm volatile("global_load_dwordx4 %0, %1, off offset:%2 sc0 sc1"
                       : "=v"(ah[ks]) : "v"(hb), "i"(ks * 64) : "memory");
        asm volatile("s_waitcnt vmcnt(0)" ::: "memory");
      }
      __builtin_amdgcn_sched_barrier(0);

      f32x4 c0 = {}, c1 = {}, c2 = {};
      #pragma unroll
      for (int ks = 0; ks < 16; ++ks) {
        f16x8 hv = __builtin_bit_cast(f16x8, ah[ks]);
        c0 = __builtin_amdgcn_mfma_f32_16x16x32_f16(__builtin_bit_cast(f16x8, wf[ks]),      hv, c0, 0, 0, 0);
        c1 = __builtin_amdgcn_mfma_f32_16x16x32_f16(__builtin_bit_cast(f16x8, wf[16 + ks]), hv, c1, 0, 0, 0);
        c2 = __builtin_amdgcn_mfma_f32_16x16x32_f16(__builtin_bit_cast(f16x8, wf[32 + ks]), hv, c2, 0, 0, 0);
      }

      // -- gates in-register (ip1 precomputed); publish h1 (one 8B store) --
      float hyv[4];
      unsigned short hx[4];
      #pragma unroll
      for (int q = 0; q < 4; ++q) {
        float rr = sigmoid_f(i0[q] + c0[q] + (&bir4.x)[q] + (&bhr4.x)[q]);
        float zz = sigmoid_f(i1[q] + c1[q] + (&biz4.x)[q] + (&bhz4.x)[q]);
        float nn = tanh_f((i2[q] + (&bin4.x)[q]) + rr * (c2[q] + (&bhn4.x)[q]));
        float hy = (1.f - zz) * nn + zz * hfq[q];
        hfq[q] = hy;
        hyv[q] = hy;
        hx[q] = __builtin_bit_cast(unsigned short, (_Float16)hy);
      }
      const unsigned long long hw =
          (unsigned long long)hx[0] | ((unsigned long long)hx[1] << 16) |
          ((unsigned long long)hx[2] << 32) | ((unsigned long long)hx[3] << 48);
      __hip_atomic_store(h1buf + ((size_t)((t + 1) & 1)) * 4096 + (size_t)bb * 128 + (cc0 >> 2),
                         hw, __ATOMIC_RELAXED, __HIP_MEMORY_SCOPE_AGENT);
      // wave-local drain, then this wave's flag (no barrier)
      asm volatile("s_waitcnt vmcnt(0)" ::: "memory");
      if (lane == 0)
        __hip_atomic_store(fl1 + (size_t)t * NFL + p * 4 + wave, 1u,
                           __ATOMIC_RELAXED, __HIP_MEMORY_SCOPE_AGENT);

      // -- y1 float4 store, off the critical path --
      float4 yo = { hyv[0], hyv[1], hyv[2], hyv[3] };
      *(float4*)(y1 + ((size_t)bb * S_LEN + t) * HID + cc0) = yo;
      if (t == S_LEN - 1)
        *(float4*)(hlast + (size_t)bb * HID + cc0) = yo;

      // -- shadow: ip1 for step t+1 (overlaps other L1 WGs' step t) --
      if (t + 1 < S_LEN) {
        const unsigned int* f = fl0 + (size_t)(t + 1) * NFL;
        while (true) {
          unsigned v = __hip_atomic_load(f + lane, __ATOMIC_RELAXED,
                                         __HIP_MEMORY_SCOPE_AGENT);
          if (__all(v != 0)) break;
          __builtin_amdgcn_s_sleep(16);
        }
        __builtin_amdgcn_sched_barrier(0);
        uint4 ay[16];
        const char* yb = (const char*)y0h + (size_t)(t + 1) * 32768 + bbyte;
        #pragma unroll
        for (int ks = 0; ks < 16; ++ks)
          asm volatile("global_load_dwordx4 %0, %1, off offset:%2 sc0 sc1"
                       : "=v"(ay[ks]) : "v"(yb), "i"(ks * 64) : "memory");
        asm volatile("s_waitcnt vmcnt(0)" ::: "memory");
        __builtin_amdgcn_sched_barrier(0);
        i0 = {}; i1 = {}; i2 = {};
        #pragma unroll
        for (int ks = 0; ks < 16; ++ks) {
          f16x8 yv = __builtin_bit_cast(f16x8, ay[ks]);
          i0 = __builtin_amdgcn_mfma_f32_16x16x32_f16(__builtin_bit_cast(f16x8, wiB[wb + ks * 64]),        yv, i0, 0, 0, 0);
          i1 = __builtin_amdgcn_mfma_f32_16x16x32_f16(__builtin_bit_cast(f16x8, wiB[wb + (16 + ks) * 64]), yv, i1, 0, 0, 0);
          i2 = __builtin_amdgcn_mfma_f32_16x16x32_f16(__builtin_bit_cast(f16x8, wiB[wb + (32 + ks) * 64]), yv, i2, 0, 0, 0);
        }
      }
    }
  }
}

// ---------------------------------------------------------------------------
// ws layout (bytes)
// ---------------------------------------------------------------------------
#define BFWH0_OFF 0ull
#define BFWH1_OFF 1572864ull
#define BFWI1_OFF 3145728ull
#define WI0_OFF   4718592ull
#define H1_OFF    6291456ull      // 65536
#define FL0_OFF   6356992ull      // 524288 ([2048][64] dwords)
#define FL1_OFF   6881280ull      // 524288
#define Y0H_OFF   7405568ull      // 67108864
#define IP_OFF    74514432ull

template <typename IPT>
static void run_all(const float* x,
                    const float* Wi0, const float* bi0, const float* Wh0, const float* bh0,
                    const float* Wi1, const float* bi1, const float* Wh1, const float* bh1,
                    float* out, char* ws, hipStream_t stream) {
  unsigned int* bfWh0 = (unsigned int*)(ws + BFWH0_OFF);
  unsigned int* bfWh1 = (unsigned int*)(ws + BFWH1_OFF);
  unsigned int* bfWi1 = (unsigned int*)(ws + BFWI1_OFF);
  __bf16* wi0b = (__bf16*)(ws + WI0_OFF);
  unsigned long long* h1buf = (unsigned long long*)(ws + H1_OFF);
  unsigned int* fl0 = (unsigned int*)(ws + FL0_OFF);
  unsigned int* fl1 = (unsigned int*)(ws + FL1_OFF);
  unsigned long long* y0h = (unsigned long long*)(ws + Y0H_OFF);
  IPT* ip = (IPT*)(ws + IP_OFF);
  float* y1    = out;
  float* hlast = out + (size_t)MROWS * HID;

  // zero h1 double-buffer + both flag arrays (contiguous region) each launch
  hipMemsetAsync(ws + H1_OFF, 0, 65536ull + 524288ull + 524288ull, stream);

  prep_bfrag<<<dim3(1536), dim3(256), 0, stream>>>(Wh0, bfWh0);
  prep_bfrag<<<dim3(1536), dim3(256), 0, stream>>>(Wh1, bfWh1);
  prep_bfrag<<<dim3(1536), dim3(256), 0, stream>>>(Wi1, bfWi1);
  prep_wib<<<dim3(3072), dim3(256), 0, stream>>>(Wi0, wi0b);

  gemm_ip<IPT><<<dim3(24, 1024), dim3(256), 0, stream>>>(x, wi0b, bi0, ip);
  gru_fused<IPT><<<dim3(2 * NWG), dim3(256), 0, stream>>>(
      ip, (const uint4*)bfWh0, bh0, (const uint4*)bfWh1, (const uint4*)bfWi1,
      bi1, bh1, y1, hlast, h1buf, y0h, fl0, fl1);
}

extern "C" void kernel_launch(void* const* d_in, const int* in_sizes, int n_in,
                              void* d_out, int out_size, void* d_ws, size_t ws_size,
                              hipStream_t stream) {
  const float* x   = (const float*)d_in[0];
  const float* Wi0 = (const float*)d_in[1];
  const float* bi0 = (const float*)d_in[2];
  const float* Wh0 = (const float*)d_in[3];
  const float* bh0 = (const float*)d_in[4];
  const float* Wi1 = (const float*)d_in[5];
  const float* bi1 = (const float*)d_in[6];
  const float* Wh1 = (const float*)d_in[7];
  const float* bh1 = (const float*)d_in[8];
  float* out = (float*)d_out;
  char*  ws  = (char*)d_ws;

  const size_t need_f32 = IP_OFF + (size_t)MROWS * G3 * 4;
  if (ws_size >= need_f32) {
    run_all<float>(x, Wi0, bi0, Wh0, bh0, Wi1, bi1, Wh1, bh1, out, ws, stream);
  } else {
    run_all<unsigned short>(x, Wi0, bi0, Wh0, bh0, Wi1, bi1, Wh1, bh1, out, ws, stream);
  }
}

// Round 18
// 11449.335 us; speedup vs baseline: 1.2279x; 1.0830x over previous
//
#include <hip/hip_runtime.h>
#include <hip/hip_bf16.h>

// ---------------------------------------------------------------------------
// GRU, 2 layers, B=32, S=2048, D=H=512.
//   gemm:   ip0 = x @ Wi0^T + bi0   (bf16 MFMA)                [verified]
//   fused:  32 WGs. WG 0..15 = layer-0 rec, WG 16..31 = layer-1 rec.
//   r18 = r17 (passing, 12.40 ms) + ONE change: SET-SPLIT flag polling.
//     A consumer wave (mh,set) reads only h-rows bb in [set*16,set*16+16),
//     produced solely by the 32 producer waves with the same set. All four
//     poll sites now check only those 32 flags (each twice across 64 lanes):
//       fidx = (lane&15)*4 + set + 2*((lane>>4)&1)
//     => the two batch-halves form two independent 32-wave rings; straggler
//     population halves and cross-half jitter decouples.
//   Everything else byte-for-byte r17 (per-wave flags, no loop barriers).
// ---------------------------------------------------------------------------

typedef __bf16    bf16x8 __attribute__((ext_vector_type(8)));
typedef __bf16    bf16x4 __attribute__((ext_vector_type(4)));
typedef float     f32x4  __attribute__((ext_vector_type(4)));
typedef _Float16  f16x2  __attribute__((ext_vector_type(2)));
typedef _Float16  f16x8  __attribute__((ext_vector_type(8)));

#define S_LEN 2048
#define BATCH 32
#define HID   512
#define G3    1536
#define MROWS (BATCH * S_LEN)
#define NWG   16
#define NFL   64                 // flags per step (per wave)

__device__ inline float sigmoid_f(float x) { return 1.f / (1.f + __expf(-x)); }
__device__ inline float tanh_f(float x) {
  float e = __expf(2.f * x);
  return 1.f - 2.f / (e + 1.f);
}

template <typename IPT>
__device__ inline void store_ip(IPT* p, float v) {
  if constexpr (sizeof(IPT) == 4) *p = v;
  else *p = __builtin_bit_cast(unsigned short, (__bf16)v);
}
template <typename IPT>
__device__ inline float4 load_ip4(const IPT* p) {
  if constexpr (sizeof(IPT) == 4) {
    return *(const float4*)p;
  } else {
    ushort4 u = *(const ushort4*)p;
    float4 r;
    r.x = __uint_as_float((unsigned)u.x << 16);
    r.y = __uint_as_float((unsigned)u.y << 16);
    r.z = __uint_as_float((unsigned)u.z << 16);
    r.w = __uint_as_float((unsigned)u.w << 16);
    return r;
  }
}

// ---------------------------------------------------------------------------
// prep: Wi0 fp32 -> bf16 (for ip GEMM)
// ---------------------------------------------------------------------------
__global__ void prep_wib(const float* __restrict__ W, __bf16* __restrict__ o) {
  int i = blockIdx.x * 256 + threadIdx.x;
  o[i] = (__bf16)W[i];
}

// ---------------------------------------------------------------------------
// prep: (1536,512) fp32 weight -> A-fragment order (f16 pairs), operand-swap.
// A-frag (16x16x32): lane l holds A[row][k], row = l&15, k = ks*32+(l>>4)*8+e.
// Tile (p, mh, g): A rows = g*512 + p*32 + mh*16 + (l&15).
//   dword idx = ((p*2+mh)*48 + g*16 + ks)*256 + l*4 + d ; k = ks*32+(l>>4)*8+2d
// ---------------------------------------------------------------------------
__global__ void prep_bfrag(const float* __restrict__ W, unsigned int* __restrict__ out) {
  int idx = blockIdx.x * 256 + threadIdx.x;   // grid = 393216/256 = 1536
  int p    = idx / 24576;
  int r    = idx % 24576;
  int mh   = r / 12288;
  int r2   = r % 12288;
  int frag = r2 / 256;                        // g*16 + ks
  int lq   = r2 % 256;
  int l    = lq >> 2, d = lq & 3;
  int g    = frag >> 4, ks = frag & 15;
  int row  = g * 512 + p * 32 + mh * 16 + (l & 15);
  int k    = ks * 32 + (l >> 4) * 8 + 2 * d;
  f16x2 pk = { (_Float16)W[(size_t)row * HID + k],
               (_Float16)W[(size_t)row * HID + k + 1] };
  out[idx] = __builtin_bit_cast(unsigned int, pk);
}

// ---------------------------------------------------------------------------
// ip GEMM (verified): C(M,1536)=A(M,512)@Bw(1536,512)^T + bias
// ---------------------------------------------------------------------------
template <typename IPT>
__global__ __launch_bounds__(256) void gemm_ip(
    const float* __restrict__ A, const __bf16* __restrict__ Bw,
    const float* __restrict__ bias, IPT* __restrict__ C) {
  constexpr int K = 512;
  __shared__ __align__(16) __bf16 As[64][72];
  __shared__ __align__(16) __bf16 Bs[64][72];
  const int tid  = threadIdx.x;
  const int bm   = blockIdx.y, bn = blockIdx.x;
  const int lane = tid & 63,  wave = tid >> 6;
  const int wr   = wave >> 1, wc   = wave & 1;
  f32x4 acc[2][2] = {};
  const int r = tid >> 2, q = tid & 3;
  const float*  Arow = A  + (size_t)(bm * 64 + r) * K;
  const __bf16* Brow = Bw + (size_t)(bn * 64 + r) * K;

  for (int k0 = 0; k0 < K; k0 += 64) {
    const float4* as = (const float4*)(Arow + k0);
    #pragma unroll
    for (int i = 0; i < 4; ++i) {
      float4 v = as[q + 4 * i];
      bf16x4 pkt = { (__bf16)v.x, (__bf16)v.y, (__bf16)v.z, (__bf16)v.w };
      *(bf16x4*)&As[r][4 * (q + 4 * i)] = pkt;
    }
    const uint4* bs = (const uint4*)(Brow + k0);
    uint4* bd = (uint4*)&Bs[r][0];
    bd[q]     = bs[q];
    bd[q + 4] = bs[q + 4];
    __syncthreads();

    #pragma unroll
    for (int kk = 0; kk < 64; kk += 32) {
      const int kb = kk + 8 * (lane >> 4);
      bf16x8 a0 = *(const bf16x8*)&As[wr * 32 +      (lane & 15)][kb];
      bf16x8 a1 = *(const bf16x8*)&As[wr * 32 + 16 + (lane & 15)][kb];
      bf16x8 b0 = *(const bf16x8*)&Bs[wc * 32 +      (lane & 15)][kb];
      bf16x8 b1 = *(const bf16x8*)&Bs[wc * 32 + 16 + (lane & 15)][kb];
      acc[0][0] = __builtin_amdgcn_mfma_f32_16x16x32_bf16(a0, b0, acc[0][0], 0, 0, 0);
      acc[0][1] = __builtin_amdgcn_mfma_f32_16x16x32_bf16(a0, b1, acc[0][1], 0, 0, 0);
      acc[1][0] = __builtin_amdgcn_mfma_f32_16x16x32_bf16(a1, b0, acc[1][0], 0, 0, 0);
      acc[1][1] = __builtin_amdgcn_mfma_f32_16x16x32_bf16(a1, b1, acc[1][1], 0, 0, 0);
    }
    __syncthreads();
  }

  const int row0 = bm * 64 + wr * 32 + (lane >> 4) * 4;
  const int col0 = bn * 64 + wc * 32 + (lane & 15);
  #pragma unroll
  for (int fm = 0; fm < 2; ++fm)
    #pragma unroll
    for (int fn = 0; fn < 2; ++fn) {
      int n = col0 + fn * 16;
      float bv = bias[n];
      #pragma unroll
      for (int reg = 0; reg < 4; ++reg) {
        size_t off = (size_t)(row0 + fm * 16 + reg) * G3 + n;
        store_ip<IPT>(C + off, acc[fm][fn][reg] + bv);
      }
    }
}

// ---------------------------------------------------------------------------
// fused recurrence: WG 0..15 layer 0, WG 16..31 layer 1.
// Lane (wave=(mh,set), hi=lane>>4, jj=lane&15) owns batch bb = set*16+jj and
// cols cc0..cc0+3, cc0 = p*32 + mh*16 + hi*4, for all 3 gates.
// Flags: per-wave fl[t][p*4+wave]; polls check only the 32 set-matched flags.
// ---------------------------------------------------------------------------
template <typename IPT>
__global__ __launch_bounds__(256, 1) void gru_fused(
    const IPT* __restrict__ ip0,
    const uint4* __restrict__ bfWh0,
    const float* __restrict__ bh0,
    const uint4* __restrict__ bfWh1,
    const uint4* __restrict__ bfWi1,
    const float* __restrict__ bi1,
    const float* __restrict__ bh1,
    float* __restrict__ y1,
    float* __restrict__ hlast,
    unsigned long long* __restrict__ h1buf,   // [2][32][128] 8B
    unsigned long long* __restrict__ y0h,     // [S][32][128] 8B (f16 y0 == h0)
    unsigned int* __restrict__ fl0,           // [S][64] per-wave flags
    unsigned int* __restrict__ fl1) {         // [S][64]
  __shared__ __align__(16) uint4 wiB[6144];   // L1 only (96 KB)
  const int bid = blockIdx.x, tid = threadIdx.x;
  const int lane = tid & 63, wave = tid >> 6;
  const int set = wave & 1, mh = wave >> 1;
  const int jj = lane & 15, hi = lane >> 4;
  const int bb = set * 16 + jj;               // this lane's batch
  const int bbyte = bb * 1024 + hi * 16;      // h B-frag byte base
  // set-matched flag index: covers {p in [0,16)} x {wave in {set, set+2}}
  const int fidx = (lane & 15) * 4 + set + 2 * ((lane >> 4) & 1);

  if (bid < NWG) {
    // ======================= layer 0 (single publish to y0h) ===============
    const int p = bid;
    const int cc0 = p * 32 + mh * 16 + hi * 4;     // this lane's col base
    uint4 wf[48];
    {
      const uint4* bsrc = bfWh0 + ((size_t)(p * 2 + mh) * 48) * 64 + lane;
      #pragma unroll
      for (int i = 0; i < 48; ++i) wf[i] = bsrc[i * 64];
      #pragma unroll
      for (int i = 0; i < 48; ++i)
        asm volatile("" : "+v"(wf[i].x), "+v"(wf[i].y), "+v"(wf[i].z), "+v"(wf[i].w));
    }
    const float4 bhr4 = *(const float4*)(bh0 + cc0);
    const float4 bhz4 = *(const float4*)(bh0 + 512 + cc0);
    const float4 bhn4 = *(const float4*)(bh0 + 1024 + cc0);
    float hfq[4] = {0.f, 0.f, 0.f, 0.f};

    for (int t = 0; t < S_LEN; ++t) {
      const IPT* bp = ip0 + ((size_t)bb * S_LEN + t) * G3 + cc0;
      float4 ipr = load_ip4<IPT>(bp);
      float4 ipz = load_ip4<IPT>(bp + 512);
      float4 ipn = load_ip4<IPT>(bp + 1024);
      __builtin_amdgcn_sched_barrier(0);

      f32x4 a0 = {}, a1 = {}, a2 = {};
      if (t > 0) {
        const unsigned int* f = fl0 + (size_t)(t - 1) * NFL;
        while (true) {
          unsigned v = __hip_atomic_load(f + fidx, __ATOMIC_RELAXED,
                                         __HIP_MEMORY_SCOPE_AGENT);
          if (__all(v != 0)) break;
          __builtin_amdgcn_s_sleep(1);
        }
        __builtin_amdgcn_sched_barrier(0);

        // h(t-1) B-fragments straight from y0h[t-1] (flag-guarded)
        const char* hb = (const char*)y0h + (size_t)(t - 1) * 32768 + bbyte;
        uint4 bf[16];
        #pragma unroll
        for (int ks = 0; ks < 16; ++ks)
          asm volatile("global_load_dwordx4 %0, %1, off offset:%2 sc0 sc1"
                       : "=v"(bf[ks]) : "v"(hb), "i"(ks * 64) : "memory");
        asm volatile("s_waitcnt vmcnt(0)" ::: "memory");
        __builtin_amdgcn_sched_barrier(0);

        #pragma unroll
        for (int ks = 0; ks < 16; ++ks) {
          f16x8 hv = __builtin_bit_cast(f16x8, bf[ks]);
          a0 = __builtin_amdgcn_mfma_f32_16x16x32_f16(__builtin_bit_cast(f16x8, wf[ks]),      hv, a0, 0, 0, 0);
          a1 = __builtin_amdgcn_mfma_f32_16x16x32_f16(__builtin_bit_cast(f16x8, wf[16 + ks]), hv, a1, 0, 0, 0);
          a2 = __builtin_amdgcn_mfma_f32_16x16x32_f16(__builtin_bit_cast(f16x8, wf[32 + ks]), hv, a2, 0, 0, 0);
        }
      }

      unsigned short hx[4];
      #pragma unroll
      for (int q = 0; q < 4; ++q) {
        float rr = sigmoid_f(a0[q] + (&bhr4.x)[q] + (&ipr.x)[q]);
        float zz = sigmoid_f(a1[q] + (&bhz4.x)[q] + (&ipz.x)[q]);
        float nn = tanh_f((&ipn.x)[q] + rr * (a2[q] + (&bhn4.x)[q]));
        float hy = (1.f - zz) * nn + zz * hfq[q];
        hfq[q] = hy;
        hx[q] = __builtin_bit_cast(unsigned short, (_Float16)hy);
      }
      const unsigned long long hw =
          (unsigned long long)hx[0] | ((unsigned long long)hx[1] << 16) |
          ((unsigned long long)hx[2] << 32) | ((unsigned long long)hx[3] << 48);
      __hip_atomic_store(y0h + (size_t)t * 4096 + (size_t)bb * 128 + (cc0 >> 2), hw,
                         __ATOMIC_RELAXED, __HIP_MEMORY_SCOPE_AGENT);
      // wave-local drain, then this wave's flag (no barrier)
      asm volatile("s_waitcnt vmcnt(0)" ::: "memory");
      if (lane == 0)
        __hip_atomic_store(fl0 + (size_t)t * NFL + p * 4 + wave, 1u,
                           __ATOMIC_RELAXED, __HIP_MEMORY_SCOPE_AGENT);
    }
  } else {
    // ======================= layer 1 (shadow ip1) ==========================
    const int p = bid - NWG;
    const int cc0 = p * 32 + mh * 16 + hi * 4;
    uint4 wf[48];
    {
      const uint4* bsrc = bfWh1 + ((size_t)(p * 2 + mh) * 48) * 64 + lane;
      #pragma unroll
      for (int i = 0; i < 48; ++i) wf[i] = bsrc[i * 64];
      #pragma unroll
      for (int i = 0; i < 48; ++i)
        asm volatile("" : "+v"(wf[i].x), "+v"(wf[i].y), "+v"(wf[i].z), "+v"(wf[i].w));
    }
    {
      const uint4* src = bfWi1 + (size_t)p * 6144;
      for (int i = tid; i < 6144; i += 256) wiB[i] = src[i];
    }
    const float4 bir4 = *(const float4*)(bi1 + cc0);
    const float4 biz4 = *(const float4*)(bi1 + 512 + cc0);
    const float4 bin4 = *(const float4*)(bi1 + 1024 + cc0);
    const float4 bhr4 = *(const float4*)(bh1 + cc0);
    const float4 bhz4 = *(const float4*)(bh1 + 512 + cc0);
    const float4 bhn4 = *(const float4*)(bh1 + 1024 + cc0);
    float hfq[4] = {0.f, 0.f, 0.f, 0.f};
    const int wb = mh * 3072 + lane;
    __syncthreads();                          // wiB ready (once, before loop)

    // ---- shadow prologue: ip1 for t = 0 ----
    f32x4 i0 = {}, i1 = {}, i2 = {};
    {
      const unsigned int* f = fl0;            // fl0[0]
      while (true) {
        unsigned v = __hip_atomic_load(f + fidx, __ATOMIC_RELAXED,
                                       __HIP_MEMORY_SCOPE_AGENT);
        if (__all(v != 0)) break;
        __builtin_amdgcn_s_sleep(16);
      }
      __builtin_amdgcn_sched_barrier(0);
      uint4 ay[16];
      const char* yb = (const char*)y0h + bbyte;
      #pragma unroll
      for (int ks = 0; ks < 16; ++ks)
        asm volatile("global_load_dwordx4 %0, %1, off offset:%2 sc0 sc1"
                     : "=v"(ay[ks]) : "v"(yb), "i"(ks * 64) : "memory");
      asm volatile("s_waitcnt vmcnt(0)" ::: "memory");
      __builtin_amdgcn_sched_barrier(0);
      #pragma unroll
      for (int ks = 0; ks < 16; ++ks) {
        f16x8 yv = __builtin_bit_cast(f16x8, ay[ks]);
        i0 = __builtin_amdgcn_mfma_f32_16x16x32_f16(__builtin_bit_cast(f16x8, wiB[wb + ks * 64]),        yv, i0, 0, 0, 0);
        i1 = __builtin_amdgcn_mfma_f32_16x16x32_f16(__builtin_bit_cast(f16x8, wiB[wb + (16 + ks) * 64]), yv, i1, 0, 0, 0);
        i2 = __builtin_amdgcn_mfma_f32_16x16x32_f16(__builtin_bit_cast(f16x8, wiB[wb + (32 + ks) * 64]), yv, i2, 0, 0, 0);
      }
    }

    for (int t = 0; t < S_LEN; ++t) {
      // -- wait own h1(t-1): set-matched flags only --
      if (t > 0) {
        const unsigned int* f = fl1 + (size_t)(t - 1) * NFL;
        while (true) {
          unsigned v = __hip_atomic_load(f + fidx, __ATOMIC_RELAXED,
                                         __HIP_MEMORY_SCOPE_AGENT);
          if (__all(v != 0)) break;
          __builtin_amdgcn_s_sleep(16);
        }
      }
      __builtin_amdgcn_sched_barrier(0);

      uint4 ah[16];
      {
        const char* hb = (const char*)h1buf + (t & 1) * 32768 + bbyte;
        #pragma unroll
        for (int ks = 0; ks < 16; ++ks)
          asm volatile("global_load_dwordx4 %0, %1, off offset:%2 sc0 sc1"
                       : "=v"(ah[ks]) : "v"(hb), "i"(ks * 64) : "memory");
        asm volatile("s_waitcnt vmcnt(0)" ::: "memory");
      }
      __builtin_amdgcn_sched_barrier(0);

      f32x4 c0 = {}, c1 = {}, c2 = {};
      #pragma unroll
      for (int ks = 0; ks < 16; ++ks) {
        f16x8 hv = __builtin_bit_cast(f16x8, ah[ks]);
        c0 = __builtin_amdgcn_mfma_f32_16x16x32_f16(__builtin_bit_cast(f16x8, wf[ks]),      hv, c0, 0, 0, 0);
        c1 = __builtin_amdgcn_mfma_f32_16x16x32_f16(__builtin_bit_cast(f16x8, wf[16 + ks]), hv, c1, 0, 0, 0);
        c2 = __builtin_amdgcn_mfma_f32_16x16x32_f16(__builtin_bit_cast(f16x8, wf[32 + ks]), hv, c2, 0, 0, 0);
      }

      // -- gates in-register (ip1 precomputed); publish h1 (one 8B store) --
      float hyv[4];
      unsigned short hx[4];
      #pragma unroll
      for (int q = 0; q < 4; ++q) {
        float rr = sigmoid_f(i0[q] + c0[q] + (&bir4.x)[q] + (&bhr4.x)[q]);
        float zz = sigmoid_f(i1[q] + c1[q] + (&biz4.x)[q] + (&bhz4.x)[q]);
        float nn = tanh_f((i2[q] + (&bin4.x)[q]) + rr * (c2[q] + (&bhn4.x)[q]));
        float hy = (1.f - zz) * nn + zz * hfq[q];
        hfq[q] = hy;
        hyv[q] = hy;
        hx[q] = __builtin_bit_cast(unsigned short, (_Float16)hy);
      }
      const unsigned long long hw =
          (unsigned long long)hx[0] | ((unsigned long long)hx[1] << 16) |
          ((unsigned long long)hx[2] << 32) | ((unsigned long long)hx[3] << 48);
      __hip_atomic_store(h1buf + ((size_t)((t + 1) & 1)) * 4096 + (size_t)bb * 128 + (cc0 >> 2),
                         hw, __ATOMIC_RELAXED, __HIP_MEMORY_SCOPE_AGENT);
      // wave-local drain, then this wave's flag (no barrier)
      asm volatile("s_waitcnt vmcnt(0)" ::: "memory");
      if (lane == 0)
        __hip_atomic_store(fl1 + (size_t)t * NFL + p * 4 + wave, 1u,
                           __ATOMIC_RELAXED, __HIP_MEMORY_SCOPE_AGENT);

      // -- y1 float4 store, off the critical path --
      float4 yo = { hyv[0], hyv[1], hyv[2], hyv[3] };
      *(float4*)(y1 + ((size_t)bb * S_LEN + t) * HID + cc0) = yo;
      if (t == S_LEN - 1)
        *(float4*)(hlast + (size_t)bb * HID + cc0) = yo;

      // -- shadow: ip1 for step t+1 (set-matched fl0 flags) --
      if (t + 1 < S_LEN) {
        const unsigned int* f = fl0 + (size_t)(t + 1) * NFL;
        while (true) {
          unsigned v = __hip_atomic_load(f + fidx, __ATOMIC_RELAXED,
                                         __HIP_MEMORY_SCOPE_AGENT);
          if (__all(v != 0)) break;
          __builtin_amdgcn_s_sleep(16);
        }
        __builtin_amdgcn_sched_barrier(0);
        uint4 ay[16];
        const char* yb = (const char*)y0h + (size_t)(t + 1) * 32768 + bbyte;
        #pragma unroll
        for (int ks = 0; ks < 16; ++ks)
          asm volatile("global_load_dwordx4 %0, %1, off offset:%2 sc0 sc1"
                       : "=v"(ay[ks]) : "v"(yb), "i"(ks * 64) : "memory");
        asm volatile("s_waitcnt vmcnt(0)" ::: "memory");
        __builtin_amdgcn_sched_barrier(0);
        i0 = {}; i1 = {}; i2 = {};
        #pragma unroll
        for (int ks = 0; ks < 16; ++ks) {
          f16x8 yv = __builtin_bit_cast(f16x8, ay[ks]);
          i0 = __builtin_amdgcn_mfma_f32_16x16x32_f16(__builtin_bit_cast(f16x8, wiB[wb + ks * 64]),        yv, i0, 0, 0, 0);
          i1 = __builtin_amdgcn_mfma_f32_16x16x32_f16(__builtin_bit_cast(f16x8, wiB[wb + (16 + ks) * 64]), yv, i1, 0, 0, 0);
          i2 = __builtin_amdgcn_mfma_f32_16x16x32_f16(__builtin_bit_cast(f16x8, wiB[wb + (32 + ks) * 64]), yv, i2, 0, 0, 0);
        }
      }
    }
  }
}

// ---------------------------------------------------------------------------
// ws layout (bytes)
// ---------------------------------------------------------------------------
#define BFWH0_OFF 0ull
#define BFWH1_OFF 1572864ull
#define BFWI1_OFF 3145728ull
#define WI0_OFF   4718592ull
#define H1_OFF    6291456ull      // 65536
#define FL0_OFF   6356992ull      // 524288 ([2048][64] dwords)
#define FL1_OFF   6881280ull      // 524288
#define Y0H_OFF   7405568ull      // 67108864
#define IP_OFF    74514432ull

template <typename IPT>
static void run_all(const float* x,
                    const float* Wi0, const float* bi0, const float* Wh0, const float* bh0,
                    const float* Wi1, const float* bi1, const float* Wh1, const float* bh1,
                    float* out, char* ws, hipStream_t stream) {
  unsigned int* bfWh0 = (unsigned int*)(ws + BFWH0_OFF);
  unsigned int* bfWh1 = (unsigned int*)(ws + BFWH1_OFF);
  unsigned int* bfWi1 = (unsigned int*)(ws + BFWI1_OFF);
  __bf16* wi0b = (__bf16*)(ws + WI0_OFF);
  unsigned long long* h1buf = (unsigned long long*)(ws + H1_OFF);
  unsigned int* fl0 = (unsigned int*)(ws + FL0_OFF);
  unsigned int* fl1 = (unsigned int*)(ws + FL1_OFF);
  unsigned long long* y0h = (unsigned long long*)(ws + Y0H_OFF);
  IPT* ip = (IPT*)(ws + IP_OFF);
  float* y1    = out;
  float* hlast = out + (size_t)MROWS * HID;

  // zero h1 double-buffer + both flag arrays (contiguous region) each launch
  hipMemsetAsync(ws + H1_OFF, 0, 65536ull + 524288ull + 524288ull, stream);

  prep_bfrag<<<dim3(1536), dim3(256), 0, stream>>>(Wh0, bfWh0);
  prep_bfrag<<<dim3(1536), dim3(256), 0, stream>>>(Wh1, bfWh1);
  prep_bfrag<<<dim3(1536), dim3(256), 0, stream>>>(Wi1, bfWi1);
  prep_wib<<<dim3(3072), dim3(256), 0, stream>>>(Wi0, wi0b);

  gemm_ip<IPT><<<dim3(24, 1024), dim3(256), 0, stream>>>(x, wi0b, bi0, ip);
  gru_fused<IPT><<<dim3(2 * NWG), dim3(256), 0, stream>>>(
      ip, (const uint4*)bfWh0, bh0, (const uint4*)bfWh1, (const uint4*)bfWi1,
      bi1, bh1, y1, hlast, h1buf, y0h, fl0, fl1);
}

extern "C" void kernel_launch(void* const* d_in, const int* in_sizes, int n_in,
                              void* d_out, int out_size, void* d_ws, size_t ws_size,
                              hipStream_t stream) {
  const float* x   = (const float*)d_in[0];
  const float* Wi0 = (const float*)d_in[1];
  const float* bi0 = (const float*)d_in[2];
  const float* Wh0 = (const float*)d_in[3];
  const float* bh0 = (const float*)d_in[4];
  const float* Wi1 = (const float*)d_in[5];
  const float* bi1 = (const float*)d_in[6];
  const float* Wh1 = (const float*)d_in[7];
  const float* bh1 = (const float*)d_in[8];
  float* out = (float*)d_out;
  char*  ws  = (char*)d_ws;

  const size_t need_f32 = IP_OFF + (size_t)MROWS * G3 * 4;
  if (ws_size >= need_f32) {
    run_all<float>(x, Wi0, bi0, Wh0, bh0, Wi1, bi1, Wh1, bh1, out, ws, stream);
  } else {
    run_all<unsigned short>(x, Wi0, bi0, Wh0, bh0, Wi1, bi1, Wh1, bh1, out, ws, stream);
  }
}